// Round 2
// baseline (461.153 us; speedup 1.0000x reference)
//
#include <hip/hip_runtime.h>
#include <hip/hip_bf16.h>

#define HEADS 16
#define HDIM  64
#define EMB   1024
#define NB    8
#define SEQ   1024

typedef __bf16 bf16_t;
typedef __bf16 bf16x8 __attribute__((ext_vector_type(8)));
typedef __bf16 bf16x4 __attribute__((ext_vector_type(4)));
typedef float  floatx4 __attribute__((ext_vector_type(4)));

union PkU { unsigned u; __bf16 h[2]; };

__device__ __forceinline__ bf16x8 load8bf(const bf16_t* p) { return *(const bf16x8*)p; }
__device__ __forceinline__ bf16x4 cvt4(float4 a) {
    bf16x4 r; r[0]=(bf16_t)a.x; r[1]=(bf16_t)a.y; r[2]=(bf16_t)a.z; r[3]=(bf16_t)a.w;
    return r;
}
__device__ __forceinline__ bf16x8 cvt8(float4 a, float4 b) {
    bf16x8 r;
    r[0]=(bf16_t)a.x; r[1]=(bf16_t)a.y; r[2]=(bf16_t)a.z; r[3]=(bf16_t)a.w;
    r[4]=(bf16_t)b.x; r[5]=(bf16_t)b.y; r[6]=(bf16_t)b.z; r[7]=(bf16_t)b.w;
    return r;
}

// ---------------------------------------------------------------------------
// Kernel 1: per-head projections.
// ops 0/1 (Q,K): identical math + stores to the verified round-6 version.
// op 2 (V): block remapped to (one nh, 64 consecutive l) so the transposed
// [nh][d][l] output can be LDS-staged and stored as coalesced bf16x8 rows
// instead of 2-byte scatters at 2KB stride (HBM write-amplification fix).
// ---------------------------------------------------------------------------
__global__ __launch_bounds__(256) void proj_kernel(
    const float* __restrict__ q_in, const float* __restrict__ k_in,
    const float* __restrict__ v_in,
    const float* __restrict__ Wq, const float* __restrict__ Wk,
    const float* __restrict__ Wv,
    bf16_t* __restrict__ qp, bf16_t* __restrict__ kp, bf16_t* __restrict__ vt)
{
    __shared__ __align__(16) bf16_t wl[64][72];
    __shared__ __align__(16) bf16_t lo[64][72];   // op2 transpose staging

    const int wave = threadIdx.x >> 6;
    const int lane = threadIdx.x & 63;
    const int m  = lane & 15;
    const int q4 = lane >> 4;
    const int op = blockIdx.y;

    const float* x = (op == 0) ? q_in : (op == 1) ? k_in : v_in;
    const float* W = (op == 0) ? Wq   : (op == 1) ? Wk   : Wv;

    {
        const int t  = threadIdx.x;
        const int f  = t >> 2;
        const int kg = (t & 3) * 16;
        #pragma unroll
        for (int j = 0; j < 4; ++j) {
            float4 v = *(const float4*)(W + f * 64 + kg + j * 4);
            *(bf16x4*)&wl[f][kg + j * 4] = cvt4(v);
        }
    }
    __syncthreads();

    if (op == 2) {
        // block: nh = bx>>4, l-range = (bx&15)*64 .. +64. wave handles 16 l's.
        const int nh = blockIdx.x >> 4;          // 0..127
        const int l0 = (blockIdx.x & 15) * 64;
        const int n  = nh >> 4;
        const int h  = nh & 15;

        const int la = l0 + wave * 16 + m;       // A-fragment row (query l)
        const float* xr = x + (size_t)(n * 16384 + la * 16 + h) * 64;
        float4 f0 = *(const float4*)(xr + q4 * 8);
        float4 f1 = *(const float4*)(xr + q4 * 8 + 4);
        float4 f2 = *(const float4*)(xr + 32 + q4 * 8);
        float4 f3 = *(const float4*)(xr + 32 + q4 * 8 + 4);
        bf16x8 a0 = cvt8(f0, f1);
        bf16x8 a1 = cvt8(f2, f3);

        floatx4 acc[4];
        #pragma unroll
        for (int sub = 0; sub < 4; ++sub) {
            bf16x8 b0 = load8bf(&wl[sub * 16 + m][q4 * 8]);
            bf16x8 b1 = load8bf(&wl[sub * 16 + m][32 + q4 * 8]);
            floatx4 z = {0.f, 0.f, 0.f, 0.f};
            z = __builtin_amdgcn_mfma_f32_16x16x32_bf16(a0, b0, z, 0, 0, 0);
            z = __builtin_amdgcn_mfma_f32_16x16x32_bf16(a1, b1, z, 0, 0, 0);
            acc[sub] = z;
        }

        // stage transposed tile: lo[e][l_local], C/D row = q4*4+r -> l_local
        #pragma unroll
        for (int sub = 0; sub < 4; ++sub) {
            #pragma unroll
            for (int r = 0; r < 4; r += 2) {
                PkU u; u.h[0] = (bf16_t)acc[sub][r]; u.h[1] = (bf16_t)acc[sub][r + 1];
                *(unsigned*)&lo[sub * 16 + m][wave * 16 + q4 * 4 + r] = u.u;
            }
        }
        __syncthreads();

        // coalesced store: thread t -> row e = t>>2, 16-l chunk = (t&3)*16
        const int e  = threadIdx.x >> 2;
        const int lc = (threadIdx.x & 3) * 16;
        bf16_t* dst = vt + ((size_t)nh * 64 + e) * 1024 + l0 + lc;
        *(bf16x8*)dst       = *(const bf16x8*)&lo[e][lc];
        *(bf16x8*)(dst + 8) = *(const bf16x8*)&lo[e][lc + 8];
    } else {
        const int row0 = blockIdx.x * 64 + wave * 16;

        const float* xr = x + (size_t)(row0 + m) * 64;
        float4 f0 = *(const float4*)(xr + q4 * 8);
        float4 f1 = *(const float4*)(xr + q4 * 8 + 4);
        float4 f2 = *(const float4*)(xr + 32 + q4 * 8);
        float4 f3 = *(const float4*)(xr + 32 + q4 * 8 + 4);
        bf16x8 a0 = cvt8(f0, f1);
        bf16x8 a1 = cvt8(f2, f3);

        floatx4 acc[4];
        #pragma unroll
        for (int sub = 0; sub < 4; ++sub) {
            bf16x8 b0 = load8bf(&wl[sub * 16 + m][q4 * 8]);
            bf16x8 b1 = load8bf(&wl[sub * 16 + m][32 + q4 * 8]);
            floatx4 z = {0.f, 0.f, 0.f, 0.f};
            z = __builtin_amdgcn_mfma_f32_16x16x32_bf16(a0, b0, z, 0, 0, 0);
            z = __builtin_amdgcn_mfma_f32_16x16x32_bf16(a1, b1, z, 0, 0, 0);
            acc[sub] = z;
        }

        #pragma unroll
        for (int r = 0; r < 4; ++r) {
            const int g = row0 + q4 * 4 + r;
            const int n = g >> 14;
            const int l = (g >> 4) & 1023;
            const int h = g & 15;
            const int nh = n * 16 + h;
            #pragma unroll
            for (int sub = 0; sub < 4; ++sub) {
                const int e = sub * 16 + m;
                const bf16_t val = (bf16_t)acc[sub][r];
                if (op == 0) {
                    qp[((size_t)nh * 1024 + l) * 64 + e] = val;
                } else {
                    kp[((size_t)nh * 1024 + l) * 64 + e] = val;
                }
            }
        }
    }
}

// ---------------------------------------------------------------------------
// Kernel 2: flash attention, barrier-free. Changes vs r6:
//  - block remap: nh = bid&127 so all 8 q-blocks of one nh share one XCD/L2
//    (id mod 8 == nh mod 8; 16 nh x 256KB K/V = 4MB = one XCD L2)
//  - all 8 V-fragment loads hoisted to just after exp/pack (s regs dead) so
//    their L2 latency hides under the bpermute transpose
//  - s_setprio(1) around both MFMA clusters
// ---------------------------------------------------------------------------
__global__ __launch_bounds__(256) void attn_kernel(
    bf16_t* __restrict__ qp, const bf16_t* __restrict__ kp,
    const bf16_t* __restrict__ vt)
{
    const int lane = threadIdx.x & 63;
    const int wave = threadIdx.x >> 6;
    const int m  = lane & 15;
    const int q4 = lane >> 4;

    const int nh   = blockIdx.x & 127;   // same-nh blocks -> same XCD
    const int qblk = blockIdx.x >> 7;

    bf16_t* Q = qp + (size_t)nh * 65536;
    const bf16_t* K = kp + (size_t)nh * 65536;
    const bf16_t* V = vt + (size_t)nh * 65536;   // [D][L]

    const int qb0 = qblk * 128 + wave * 32;      // tile0: queries qb0..qb0+15
    const int qb1 = qb0 + 16;                    // tile1

    bf16x8 bq0a = load8bf(Q + (qb0 + m) * 64 + q4 * 8);
    bf16x8 bq0b = load8bf(Q + (qb0 + m) * 64 + 32 + q4 * 8);
    bf16x8 bq1a = load8bf(Q + (qb1 + m) * 64 + q4 * 8);
    bf16x8 bq1b = load8bf(Q + (qb1 + m) * 64 + 32 + q4 * 8);

    floatx4 o0[4], o1[4];
    #pragma unroll
    for (int i = 0; i < 4; ++i) {
        o0[i] = (floatx4){0.f, 0.f, 0.f, 0.f};
        o1[i] = (floatx4){0.f, 0.f, 0.f, 0.f};
    }
    float l0 = 0.f, l1 = 0.f;
    const float CE = 1.4426950408889634f * 0.03125f;   // log2(e)/sqrt(1024)

    for (int kt = 0; kt < 16; ++kt) {
        const int kb = kt * 64;

        // S^T[key][q]: A = K-fragment (key rows), B = Q-fragment (q cols)
        floatx4 s0[4], s1[4];
        __builtin_amdgcn_s_setprio(1);
        #pragma unroll
        for (int sk = 0; sk < 4; ++sk) {
            bf16x8 ka0 = load8bf(K + (kb + sk * 16 + m) * 64 + q4 * 8);
            bf16x8 ka1 = load8bf(K + (kb + sk * 16 + m) * 64 + 32 + q4 * 8);
            floatx4 z = {0.f, 0.f, 0.f, 0.f};
            z = __builtin_amdgcn_mfma_f32_16x16x32_bf16(ka0, bq0a, z, 0, 0, 0);
            z = __builtin_amdgcn_mfma_f32_16x16x32_bf16(ka1, bq0b, z, 0, 0, 0);
            s0[sk] = z;
            floatx4 y = {0.f, 0.f, 0.f, 0.f};
            y = __builtin_amdgcn_mfma_f32_16x16x32_bf16(ka0, bq1a, y, 0, 0, 0);
            y = __builtin_amdgcn_mfma_f32_16x16x32_bf16(ka1, bq1b, y, 0, 0, 0);
            s1[sk] = y;
        }
        __builtin_amdgcn_s_setprio(0);

        // p = exp2(s*CE); per-lane l accumulation
        unsigned pk0[2][4], pk1[2][4];
        #pragma unroll
        for (int c = 0; c < 2; ++c) {
            #pragma unroll
            for (int r = 0; r < 4; ++r) {
                float a0 = exp2f(s0[2 * c][r] * CE);
                float a1 = exp2f(s0[2 * c + 1][r] * CE);
                l0 += a0 + a1;
                PkU u; u.h[0] = (bf16_t)a0; u.h[1] = (bf16_t)a1;
                pk0[c][r] = u.u;
                float b0 = exp2f(s1[2 * c][r] * CE);
                float b1 = exp2f(s1[2 * c + 1][r] * CE);
                l1 += b0 + b1;
                PkU v; v.h[0] = (bf16_t)b0; v.h[1] = (bf16_t)b1;
                pk1[c][r] = v.u;
            }
        }

        // hoist ALL V-fragment loads here: s0/s1 are dead (pressure ~96+temps),
        // and the ~L2 latency hides under the bpermute transpose below.
        bf16x8 va[8];
        #pragma unroll
        for (int sd = 0; sd < 4; ++sd) {
            va[2 * sd]     = load8bf(V + (sd * 16 + m) * 1024 + kb + q4 * 8);
            va[2 * sd + 1] = load8bf(V + (sd * 16 + m) * 1024 + kb + 32 + q4 * 8);
        }

        // in-register transpose (verified element-wise, unchanged)
        bf16x8 bp0[2], bp1[2];
        const int hsel = q4 >> 1;
        #pragma unroll
        for (int c = 0; c < 2; ++c) {
            #pragma unroll
            for (int j = 0; j < 8; ++j) {
                const int src = m + 16 * ((2 * q4 + (j >> 2)) & 3);
                PkU u; u.u = (unsigned)__shfl((int)pk0[c][j & 3], src, 64);
                bp0[c][j] = u.h[hsel];
                PkU v; v.u = (unsigned)__shfl((int)pk1[c][j & 3], src, 64);
                bp1[c][j] = v.h[hsel];
            }
        }

        // O^T[d][q] += V^T-frag x P-frag
        __builtin_amdgcn_s_setprio(1);
        #pragma unroll
        for (int sd = 0; sd < 4; ++sd) {
            o0[sd] = __builtin_amdgcn_mfma_f32_16x16x32_bf16(va[2 * sd],     bp0[0], o0[sd], 0, 0, 0);
            o0[sd] = __builtin_amdgcn_mfma_f32_16x16x32_bf16(va[2 * sd + 1], bp0[1], o0[sd], 0, 0, 0);
            o1[sd] = __builtin_amdgcn_mfma_f32_16x16x32_bf16(va[2 * sd],     bp1[0], o1[sd], 0, 0, 0);
            o1[sd] = __builtin_amdgcn_mfma_f32_16x16x32_bf16(va[2 * sd + 1], bp1[1], o1[sd], 0, 0, 0);
        }
        __builtin_amdgcn_s_setprio(0);
    }

    // final l reduction: keys are spread across the 4 q4-groups only
    l0 += __shfl_xor(l0, 16, 64); l0 += __shfl_xor(l0, 32, 64);
    l1 += __shfl_xor(l1, 16, 64); l1 += __shfl_xor(l1, 32, 64);
    const float i0 = 1.0f / l0, i1 = 1.0f / l1;

    #pragma unroll
    for (int sd = 0; sd < 4; ++sd) {
        bf16x4 w0, w1;
        #pragma unroll
        for (int r = 0; r < 4; ++r) {
            w0[r] = (bf16_t)(o0[sd][r] * i0);
            w1[r] = (bf16_t)(o1[sd][r] * i1);
        }
        *(bf16x4*)(Q + (size_t)(qb0 + m) * 64 + sd * 16 + q4 * 4) = w0;
        *(bf16x4*)(Q + (size_t)(qb1 + m) * 64 + sd * 16 + q4 * 4) = w1;
    }
}

// ---------------------------------------------------------------------------
// Kernel 3a: one-shot Wo fp32 -> bf16 (into the dead vt region).
// ---------------------------------------------------------------------------
__global__ __launch_bounds__(256) void wocvt_kernel(
    const float* __restrict__ Wo, bf16_t* __restrict__ wo_bf)
{
    const int i = (blockIdx.x * 256 + threadIdx.x) * 8;
    float4 f0 = *(const float4*)(Wo + i);
    float4 f1 = *(const float4*)(Wo + i + 4);
    *(bf16x8*)(wo_bf + i) = cvt8(f0, f1);
}

// ---------------------------------------------------------------------------
// Kernel 3b: out(fp32) = AO @ Wo^T, Wo pre-converted to bf16.
// No LDS, no barriers: B-fragments loaded straight from the 2MB L2-resident
// wo_bf. XCD-chunked swizzle gives each XCD a contiguous 16-row-block range
// (2MB A-slice + 2MB Wo resident per L2). Same accumulation order as r6.
// ---------------------------------------------------------------------------
__global__ __launch_bounds__(256) void outproj_kernel(
    const bf16_t* __restrict__ aoq, const bf16_t* __restrict__ wo_bf,
    float* __restrict__ out)
{
    const int wave = threadIdx.x >> 6;
    const int lane = threadIdx.x & 63;
    const int m  = lane & 15;
    const int q4 = lane >> 4;

    // grid (16,128): id = by*16+bx; XCD-chunk swizzle (2048 % 8 == 0, bijective)
    const int id = blockIdx.y * 16 + blockIdx.x;
    const int sw = (id & 7) * 256 + (id >> 3);
    const int bx = sw & 15;
    const int by = sw >> 4;

    const int row0 = by * 64 + wave * 16;
    const int col0 = bx * 64;

    const int ga  = row0 + m;
    const int n_a = ga >> 10;
    const int q_a = ga & 1023;

    floatx4 acc[4];
    #pragma unroll
    for (int i = 0; i < 4; ++i) acc[i] = (floatx4){0.f, 0.f, 0.f, 0.f};

    for (int h = 0; h < 16; ++h) {
        const bf16_t* arow = aoq + ((size_t)(n_a * 16 + h) * 1024 + q_a) * 64;
        bf16x8 a0 = load8bf(arow + q4 * 8);
        bf16x8 a1 = load8bf(arow + 32 + q4 * 8);
        const int kc = h * 64;
        #pragma unroll
        for (int sub = 0; sub < 4; ++sub) {
            const bf16_t* wrow = wo_bf + (size_t)(col0 + sub * 16 + m) * 1024 + kc;
            bf16x8 b0 = load8bf(wrow + q4 * 8);
            bf16x8 b1 = load8bf(wrow + 32 + q4 * 8);
            acc[sub] = __builtin_amdgcn_mfma_f32_16x16x32_bf16(a0, b0, acc[sub], 0, 0, 0);
            acc[sub] = __builtin_amdgcn_mfma_f32_16x16x32_bf16(a1, b1, acc[sub], 0, 0, 0);
        }
    }

    #pragma unroll
    for (int r = 0; r < 4; ++r) {
        const int g = row0 + q4 * 4 + r;
        #pragma unroll
        for (int sub = 0; sub < 4; ++sub)
            out[(size_t)g * 1024 + col0 + sub * 16 + m] = acc[sub][r];
    }
}

// ---------------------------------------------------------------------------
extern "C" void kernel_launch(void* const* d_in, const int* in_sizes, int n_in,
                              void* d_out, int out_size, void* d_ws, size_t ws_size,
                              hipStream_t stream) {
    const float* key   = (const float*)d_in[0];
    const float* query = (const float*)d_in[1];
    const float* value = (const float*)d_in[2];
    // d_in[3] = mask — faithfully ignored per the reference
    const float* Wq = (const float*)d_in[4];
    const float* Wk = (const float*)d_in[5];
    const float* Wv = (const float*)d_in[6];
    const float* Wo = (const float*)d_in[7];

    const size_t TENS = (size_t)NB * SEQ * EMB;   // 8388608
    bf16_t* qp = (bf16_t*)d_ws;                   // [N*H][L][D]; becomes AO in-place
    bf16_t* vt = qp + TENS;                       // [N*H][D][L]; reused for wo_bf after attn
    bf16_t* kp = (bf16_t*)d_out;                  // staged in d_out, dead before outproj

    hipLaunchKernelGGL(proj_kernel, dim3(2048, 3), dim3(256), 0, stream,
                       query, key, value, Wq, Wk, Wv, qp, kp, vt);
    hipLaunchKernelGGL(attn_kernel, dim3(1024), dim3(256), 0, stream, qp, kp, vt);
    hipLaunchKernelGGL(wocvt_kernel, dim3(512), dim3(256), 0, stream, Wo, vt);
    hipLaunchKernelGGL(outproj_kernel, dim3(16, 128), dim3(256), 0, stream,
                       qp, vt, (float*)d_out);
}

// Round 3
// 452.771 us; speedup vs baseline: 1.0185x; 1.0185x over previous
//
#include <hip/hip_runtime.h>
#include <hip/hip_bf16.h>

#define HEADS 16
#define HDIM  64
#define EMB   1024
#define NB    8
#define SEQ   1024

typedef __bf16 bf16_t;
typedef __bf16 bf16x8 __attribute__((ext_vector_type(8)));
typedef __bf16 bf16x4 __attribute__((ext_vector_type(4)));
typedef float  floatx4 __attribute__((ext_vector_type(4)));

union PkU { unsigned u; __bf16 h[2]; };

__device__ __forceinline__ bf16x8 load8bf(const bf16_t* p) { return *(const bf16x8*)p; }
__device__ __forceinline__ bf16x4 cvt4(float4 a) {
    bf16x4 r; r[0]=(bf16_t)a.x; r[1]=(bf16_t)a.y; r[2]=(bf16_t)a.z; r[3]=(bf16_t)a.w;
    return r;
}
__device__ __forceinline__ bf16x8 cvt8(float4 a, float4 b) {
    bf16x8 r;
    r[0]=(bf16_t)a.x; r[1]=(bf16_t)a.y; r[2]=(bf16_t)a.z; r[3]=(bf16_t)a.w;
    r[4]=(bf16_t)b.x; r[5]=(bf16_t)b.y; r[6]=(bf16_t)b.z; r[7]=(bf16_t)b.w;
    return r;
}

// ---------------------------------------------------------------------------
// Kernel 1: per-head projections (identical to round-2 passing version).
// ---------------------------------------------------------------------------
__global__ __launch_bounds__(256) void proj_kernel(
    const float* __restrict__ q_in, const float* __restrict__ k_in,
    const float* __restrict__ v_in,
    const float* __restrict__ Wq, const float* __restrict__ Wk,
    const float* __restrict__ Wv,
    bf16_t* __restrict__ qp, bf16_t* __restrict__ kp, bf16_t* __restrict__ vt)
{
    __shared__ __align__(16) bf16_t wl[64][72];
    __shared__ __align__(16) bf16_t lo[64][72];   // op2 transpose staging

    const int wave = threadIdx.x >> 6;
    const int lane = threadIdx.x & 63;
    const int m  = lane & 15;
    const int q4 = lane >> 4;
    const int op = blockIdx.y;

    const float* x = (op == 0) ? q_in : (op == 1) ? k_in : v_in;
    const float* W = (op == 0) ? Wq   : (op == 1) ? Wk   : Wv;

    {
        const int t  = threadIdx.x;
        const int f  = t >> 2;
        const int kg = (t & 3) * 16;
        #pragma unroll
        for (int j = 0; j < 4; ++j) {
            float4 v = *(const float4*)(W + f * 64 + kg + j * 4);
            *(bf16x4*)&wl[f][kg + j * 4] = cvt4(v);
        }
    }
    __syncthreads();

    if (op == 2) {
        const int nh = blockIdx.x >> 4;          // 0..127
        const int l0 = (blockIdx.x & 15) * 64;
        const int n  = nh >> 4;
        const int h  = nh & 15;

        const int la = l0 + wave * 16 + m;
        const float* xr = x + (size_t)(n * 16384 + la * 16 + h) * 64;
        float4 f0 = *(const float4*)(xr + q4 * 8);
        float4 f1 = *(const float4*)(xr + q4 * 8 + 4);
        float4 f2 = *(const float4*)(xr + 32 + q4 * 8);
        float4 f3 = *(const float4*)(xr + 32 + q4 * 8 + 4);
        bf16x8 a0 = cvt8(f0, f1);
        bf16x8 a1 = cvt8(f2, f3);

        floatx4 acc[4];
        #pragma unroll
        for (int sub = 0; sub < 4; ++sub) {
            bf16x8 b0 = load8bf(&wl[sub * 16 + m][q4 * 8]);
            bf16x8 b1 = load8bf(&wl[sub * 16 + m][32 + q4 * 8]);
            floatx4 z = {0.f, 0.f, 0.f, 0.f};
            z = __builtin_amdgcn_mfma_f32_16x16x32_bf16(a0, b0, z, 0, 0, 0);
            z = __builtin_amdgcn_mfma_f32_16x16x32_bf16(a1, b1, z, 0, 0, 0);
            acc[sub] = z;
        }

        #pragma unroll
        for (int sub = 0; sub < 4; ++sub) {
            #pragma unroll
            for (int r = 0; r < 4; r += 2) {
                PkU u; u.h[0] = (bf16_t)acc[sub][r]; u.h[1] = (bf16_t)acc[sub][r + 1];
                *(unsigned*)&lo[sub * 16 + m][wave * 16 + q4 * 4 + r] = u.u;
            }
        }
        __syncthreads();

        const int e  = threadIdx.x >> 2;
        const int lc = (threadIdx.x & 3) * 16;
        bf16_t* dst = vt + ((size_t)nh * 64 + e) * 1024 + l0 + lc;
        *(bf16x8*)dst       = *(const bf16x8*)&lo[e][lc];
        *(bf16x8*)(dst + 8) = *(const bf16x8*)&lo[e][lc + 8];
    } else {
        const int row0 = blockIdx.x * 64 + wave * 16;

        const float* xr = x + (size_t)(row0 + m) * 64;
        float4 f0 = *(const float4*)(xr + q4 * 8);
        float4 f1 = *(const float4*)(xr + q4 * 8 + 4);
        float4 f2 = *(const float4*)(xr + 32 + q4 * 8);
        float4 f3 = *(const float4*)(xr + 32 + q4 * 8 + 4);
        bf16x8 a0 = cvt8(f0, f1);
        bf16x8 a1 = cvt8(f2, f3);

        floatx4 acc[4];
        #pragma unroll
        for (int sub = 0; sub < 4; ++sub) {
            bf16x8 b0 = load8bf(&wl[sub * 16 + m][q4 * 8]);
            bf16x8 b1 = load8bf(&wl[sub * 16 + m][32 + q4 * 8]);
            floatx4 z = {0.f, 0.f, 0.f, 0.f};
            z = __builtin_amdgcn_mfma_f32_16x16x32_bf16(a0, b0, z, 0, 0, 0);
            z = __builtin_amdgcn_mfma_f32_16x16x32_bf16(a1, b1, z, 0, 0, 0);
            acc[sub] = z;
        }

        #pragma unroll
        for (int r = 0; r < 4; ++r) {
            const int g = row0 + q4 * 4 + r;
            const int n = g >> 14;
            const int l = (g >> 4) & 1023;
            const int h = g & 15;
            const int nh = n * 16 + h;
            #pragma unroll
            for (int sub = 0; sub < 4; ++sub) {
                const int e = sub * 16 + m;
                const bf16_t val = (bf16_t)acc[sub][r];
                if (op == 0) {
                    qp[((size_t)nh * 1024 + l) * 64 + e] = val;
                } else {
                    kp[((size_t)nh * 1024 + l) * 64 + e] = val;
                }
            }
        }
    }
}

// ---------------------------------------------------------------------------
// Kernel 2: flash attention, LDS-staged double-buffered K/V (2-phase pipeline).
//  - K/V tile (8KB each) staged ONCE per block via global_load_lds width=16,
//    shared by all 4 waves (removes the 4x redundant per-wave global loads)
//  - stage for kt+1 issued BEFORE compute of kt; one __syncthreads per tile
//    (its vmcnt drain is the pipeline wait) -> HBM/L2 latency hidden
//  - global SOURCE pre-swizzled chunk^(row&7); fragment ds_reads use the same
//    XOR -> ds_read_b128 at the 8-cycle bank floor (rule #21 both-sides)
//  - numerics bit-identical: staged bytes are exact copies
// ---------------------------------------------------------------------------
__global__ __launch_bounds__(256, 4) void attn_kernel(
    bf16_t* __restrict__ qp, const bf16_t* __restrict__ kp,
    const bf16_t* __restrict__ vt)
{
    __shared__ __align__(16) bf16_t kl[2][64][64];
    __shared__ __align__(16) bf16_t vl[2][64][64];

    const int lane = threadIdx.x & 63;
    const int wave = threadIdx.x >> 6;
    const int m  = lane & 15;
    const int q4 = lane >> 4;

    const int nh   = blockIdx.x & 127;   // same-nh blocks -> same XCD (FETCH win, kept)
    const int qblk = blockIdx.x >> 7;

    bf16_t* Q = qp + (size_t)nh * 65536;
    const bf16_t* K = kp + (size_t)nh * 65536;
    const bf16_t* V = vt + (size_t)nh * 65536;   // [D][L]

    const int qb0 = qblk * 128 + wave * 32;
    const int qb1 = qb0 + 16;

    // staging lane decomposition: lane -> (row-in-8-group, 16B slot)
    const int srow  = lane >> 3;         // 0..7
    const int sslot = lane & 7;          // 0..7
    const int ch    = sslot ^ srow;      // pre-swizzled global chunk (row&7 == srow)

    // stage K and V tile kt (kb = kt*64) into buffer b; wave w covers rows w*16..w*16+15
    auto stage = [&](int b, int kb) {
        #pragma unroll
        for (int i = 0; i < 2; ++i) {
            const int rbase = wave * 16 + i * 8;
            const int row   = rbase + srow;
            __builtin_amdgcn_global_load_lds(
                (const __attribute__((address_space(1))) unsigned int*)(K + (size_t)(kb + row) * 64 + ch * 8),
                (__attribute__((address_space(3))) unsigned int*)(&kl[b][rbase][0]),
                16, 0, 0);
            __builtin_amdgcn_global_load_lds(
                (const __attribute__((address_space(1))) unsigned int*)(V + (size_t)row * 1024 + kb + ch * 8),
                (__attribute__((address_space(3))) unsigned int*)(&vl[b][rbase][0]),
                16, 0, 0);
        }
    };

    stage(0, 0);   // prologue: tile 0 in flight

    bf16x8 bq0a = load8bf(Q + (qb0 + m) * 64 + q4 * 8);
    bf16x8 bq0b = load8bf(Q + (qb0 + m) * 64 + 32 + q4 * 8);
    bf16x8 bq1a = load8bf(Q + (qb1 + m) * 64 + q4 * 8);
    bf16x8 bq1b = load8bf(Q + (qb1 + m) * 64 + 32 + q4 * 8);

    floatx4 o0[4], o1[4];
    #pragma unroll
    for (int i = 0; i < 4; ++i) {
        o0[i] = (floatx4){0.f, 0.f, 0.f, 0.f};
        o1[i] = (floatx4){0.f, 0.f, 0.f, 0.f};
    }
    float l0 = 0.f, l1 = 0.f;
    const float CE = 1.4426950408889634f * 0.03125f;   // log2(e)/sqrt(1024)

    // per-lane swizzled fragment column offsets (elements)
    const int c0 = (q4 ^ (m & 7)) * 8;
    const int c1 = ((q4 + 4) ^ (m & 7)) * 8;

    int cur = 0;
    __syncthreads();   // drains prologue stage (vmcnt 0) + barrier

    for (int kt = 0; kt < 16; ++kt) {
        if (kt < 15) stage(cur ^ 1, (kt + 1) * 64);   // next tile in flight under compute

        // S^T[key][q] from LDS K
        floatx4 s0[4], s1[4];
        __builtin_amdgcn_s_setprio(1);
        #pragma unroll
        for (int sk = 0; sk < 4; ++sk) {
            bf16x8 ka0 = load8bf(&kl[cur][sk * 16 + m][c0]);
            bf16x8 ka1 = load8bf(&kl[cur][sk * 16 + m][c1]);
            floatx4 z = {0.f, 0.f, 0.f, 0.f};
            z = __builtin_amdgcn_mfma_f32_16x16x32_bf16(ka0, bq0a, z, 0, 0, 0);
            z = __builtin_amdgcn_mfma_f32_16x16x32_bf16(ka1, bq0b, z, 0, 0, 0);
            s0[sk] = z;
            floatx4 y = {0.f, 0.f, 0.f, 0.f};
            y = __builtin_amdgcn_mfma_f32_16x16x32_bf16(ka0, bq1a, y, 0, 0, 0);
            y = __builtin_amdgcn_mfma_f32_16x16x32_bf16(ka1, bq1b, y, 0, 0, 0);
            s1[sk] = y;
        }
        __builtin_amdgcn_s_setprio(0);

        // p = exp2(s*CE); per-lane l accumulation
        unsigned pk0[2][4], pk1[2][4];
        #pragma unroll
        for (int c = 0; c < 2; ++c) {
            #pragma unroll
            for (int r = 0; r < 4; ++r) {
                float a0 = exp2f(s0[2 * c][r] * CE);
                float a1 = exp2f(s0[2 * c + 1][r] * CE);
                l0 += a0 + a1;
                PkU u; u.h[0] = (bf16_t)a0; u.h[1] = (bf16_t)a1;
                pk0[c][r] = u.u;
                float b0 = exp2f(s1[2 * c][r] * CE);
                float b1 = exp2f(s1[2 * c + 1][r] * CE);
                l1 += b0 + b1;
                PkU v; v.h[0] = (bf16_t)b0; v.h[1] = (bf16_t)b1;
                pk1[c][r] = v.u;
            }
        }

        // V fragments from LDS, issued before the transpose so the ds_read
        // latency hides under the 32 bpermutes
        bf16x8 va[8];
        #pragma unroll
        for (int sd = 0; sd < 4; ++sd) {
            va[2 * sd]     = load8bf(&vl[cur][sd * 16 + m][c0]);
            va[2 * sd + 1] = load8bf(&vl[cur][sd * 16 + m][c1]);
        }

        // in-register transpose (verified element-wise, unchanged)
        bf16x8 bp0[2], bp1[2];
        const int hsel = q4 >> 1;
        #pragma unroll
        for (int c = 0; c < 2; ++c) {
            #pragma unroll
            for (int j = 0; j < 8; ++j) {
                const int src = m + 16 * ((2 * q4 + (j >> 2)) & 3);
                PkU u; u.u = (unsigned)__shfl((int)pk0[c][j & 3], src, 64);
                bp0[c][j] = u.h[hsel];
                PkU v; v.u = (unsigned)__shfl((int)pk1[c][j & 3], src, 64);
                bp1[c][j] = v.h[hsel];
            }
        }

        // O^T[d][q] += V^T-frag x P-frag
        __builtin_amdgcn_s_setprio(1);
        #pragma unroll
        for (int sd = 0; sd < 4; ++sd) {
            o0[sd] = __builtin_amdgcn_mfma_f32_16x16x32_bf16(va[2 * sd],     bp0[0], o0[sd], 0, 0, 0);
            o0[sd] = __builtin_amdgcn_mfma_f32_16x16x32_bf16(va[2 * sd + 1], bp0[1], o0[sd], 0, 0, 0);
            o1[sd] = __builtin_amdgcn_mfma_f32_16x16x32_bf16(va[2 * sd],     bp1[0], o1[sd], 0, 0, 0);
            o1[sd] = __builtin_amdgcn_mfma_f32_16x16x32_bf16(va[2 * sd + 1], bp1[1], o1[sd], 0, 0, 0);
        }
        __builtin_amdgcn_s_setprio(0);

        __syncthreads();   // waits stage(cur^1) complete + all reads of cur done
        cur ^= 1;
    }

    // final l reduction: keys are spread across the 4 q4-groups only
    l0 += __shfl_xor(l0, 16, 64); l0 += __shfl_xor(l0, 32, 64);
    l1 += __shfl_xor(l1, 16, 64); l1 += __shfl_xor(l1, 32, 64);
    const float i0 = 1.0f / l0, i1 = 1.0f / l1;

    #pragma unroll
    for (int sd = 0; sd < 4; ++sd) {
        bf16x4 w0, w1;
        #pragma unroll
        for (int r = 0; r < 4; ++r) {
            w0[r] = (bf16_t)(o0[sd][r] * i0);
            w1[r] = (bf16_t)(o1[sd][r] * i1);
        }
        *(bf16x4*)(Q + (size_t)(qb0 + m) * 64 + sd * 16 + q4 * 4) = w0;
        *(bf16x4*)(Q + (size_t)(qb1 + m) * 64 + sd * 16 + q4 * 4) = w1;
    }
}

// ---------------------------------------------------------------------------
// Kernel 3: out(fp32) = AO @ Wo^T. BYTE-IDENTICAL to the round-0 PASSING
// version (the global-B variant regressed ~40us; reverted).
// ---------------------------------------------------------------------------
__global__ __launch_bounds__(256) void outproj_kernel(
    const bf16_t* __restrict__ aoq, const float* __restrict__ Wo,
    float* __restrict__ out)
{
    __shared__ __align__(16) bf16_t wl[64][72];

    const int wave = threadIdx.x >> 6;
    const int lane = threadIdx.x & 63;
    const int m  = lane & 15;
    const int q4 = lane >> 4;

    const int row0 = blockIdx.x * 64 + wave * 16;
    const int col0 = blockIdx.y * 64;

    const int ga = row0 + m;
    const int n_a = ga >> 10;
    const int q_a = ga & 1023;

    const int ts_f  = threadIdx.x >> 2;
    const int ts_kg = (threadIdx.x & 3) * 16;

    floatx4 acc[4];
    #pragma unroll
    for (int i = 0; i < 4; ++i) acc[i] = (floatx4){0.f, 0.f, 0.f, 0.f};

    for (int kc = 0; kc < 1024; kc += 64) {
        __syncthreads();
        #pragma unroll
        for (int j = 0; j < 4; ++j) {
            float4 v = *(const float4*)(Wo + (size_t)(col0 + ts_f) * 1024 + kc + ts_kg + j * 4);
            *(bf16x4*)&wl[ts_f][ts_kg + j * 4] = cvt4(v);
        }
        __syncthreads();

        const int h = kc >> 6;
        const bf16_t* arow = aoq + ((size_t)(n_a * 16 + h) * 1024 + q_a) * 64;
        bf16x8 a0 = load8bf(arow + q4 * 8);
        bf16x8 a1 = load8bf(arow + 32 + q4 * 8);
        #pragma unroll
        for (int sub = 0; sub < 4; ++sub) {
            bf16x8 b0 = load8bf(&wl[sub * 16 + m][q4 * 8]);
            bf16x8 b1 = load8bf(&wl[sub * 16 + m][32 + q4 * 8]);
            acc[sub] = __builtin_amdgcn_mfma_f32_16x16x32_bf16(a0, b0, acc[sub], 0, 0, 0);
            acc[sub] = __builtin_amdgcn_mfma_f32_16x16x32_bf16(a1, b1, acc[sub], 0, 0, 0);
        }
    }

    #pragma unroll
    for (int r = 0; r < 4; ++r) {
        const int g = row0 + q4 * 4 + r;
        #pragma unroll
        for (int sub = 0; sub < 4; ++sub)
            out[(size_t)g * 1024 + col0 + sub * 16 + m] = acc[sub][r];
    }
}

// ---------------------------------------------------------------------------
extern "C" void kernel_launch(void* const* d_in, const int* in_sizes, int n_in,
                              void* d_out, int out_size, void* d_ws, size_t ws_size,
                              hipStream_t stream) {
    const float* key   = (const float*)d_in[0];
    const float* query = (const float*)d_in[1];
    const float* value = (const float*)d_in[2];
    // d_in[3] = mask — faithfully ignored per the reference
    const float* Wq = (const float*)d_in[4];
    const float* Wk = (const float*)d_in[5];
    const float* Wv = (const float*)d_in[6];
    const float* Wo = (const float*)d_in[7];

    const size_t TENS = (size_t)NB * SEQ * EMB;   // 8388608
    bf16_t* qp = (bf16_t*)d_ws;                   // [N*H][L][D]; becomes AO in-place
    bf16_t* vt = qp + TENS;                       // [N*H][D][L]
    bf16_t* kp = (bf16_t*)d_out;                  // staged in d_out, dead before outproj

    hipLaunchKernelGGL(proj_kernel, dim3(2048, 3), dim3(256), 0, stream,
                       query, key, value, Wq, Wk, Wv, qp, kp, vt);
    hipLaunchKernelGGL(attn_kernel, dim3(1024), dim3(256), 0, stream, qp, kp, vt);
    hipLaunchKernelGGL(outproj_kernel, dim3(128, 16), dim3(256), 0, stream,
                       qp, Wo, (float*)d_out);
}

// Round 4
// 333.553 us; speedup vs baseline: 1.3825x; 1.3574x over previous
//
#include <hip/hip_runtime.h>
#include <hip/hip_bf16.h>

#define HEADS 16
#define HDIM  64
#define EMB   1024
#define NB    8
#define SEQ   1024

typedef __bf16 bf16_t;
typedef __bf16 bf16x8 __attribute__((ext_vector_type(8)));
typedef __bf16 bf16x4 __attribute__((ext_vector_type(4)));
typedef float  floatx4 __attribute__((ext_vector_type(4)));

union PkU { unsigned u; __bf16 h[2]; };

__device__ __forceinline__ bf16x8 load8bf(const bf16_t* p) { return *(const bf16x8*)p; }
__device__ __forceinline__ bf16x4 cvt4(float4 a) {
    bf16x4 r; r[0]=(bf16_t)a.x; r[1]=(bf16_t)a.y; r[2]=(bf16_t)a.z; r[3]=(bf16_t)a.w;
    return r;
}
__device__ __forceinline__ bf16x8 cvt8(float4 a, float4 b) {
    bf16x8 r;
    r[0]=(bf16_t)a.x; r[1]=(bf16_t)a.y; r[2]=(bf16_t)a.z; r[3]=(bf16_t)a.w;
    r[4]=(bf16_t)b.x; r[5]=(bf16_t)b.y; r[6]=(bf16_t)b.z; r[7]=(bf16_t)b.w;
    return r;
}

// ---------------------------------------------------------------------------
// Kernel 1: per-head projections (identical to round-2/3 passing version).
// ---------------------------------------------------------------------------
__global__ __launch_bounds__(256) void proj_kernel(
    const float* __restrict__ q_in, const float* __restrict__ k_in,
    const float* __restrict__ v_in,
    const float* __restrict__ Wq, const float* __restrict__ Wk,
    const float* __restrict__ Wv,
    bf16_t* __restrict__ qp, bf16_t* __restrict__ kp, bf16_t* __restrict__ vt)
{
    __shared__ __align__(16) bf16_t wl[64][72];
    __shared__ __align__(16) bf16_t lo[64][72];   // op2 transpose staging

    const int wave = threadIdx.x >> 6;
    const int lane = threadIdx.x & 63;
    const int m  = lane & 15;
    const int q4 = lane >> 4;
    const int op = blockIdx.y;

    const float* x = (op == 0) ? q_in : (op == 1) ? k_in : v_in;
    const float* W = (op == 0) ? Wq   : (op == 1) ? Wk   : Wv;

    {
        const int t  = threadIdx.x;
        const int f  = t >> 2;
        const int kg = (t & 3) * 16;
        #pragma unroll
        for (int j = 0; j < 4; ++j) {
            float4 v = *(const float4*)(W + f * 64 + kg + j * 4);
            *(bf16x4*)&wl[f][kg + j * 4] = cvt4(v);
        }
    }
    __syncthreads();

    if (op == 2) {
        const int nh = blockIdx.x >> 4;          // 0..127
        const int l0 = (blockIdx.x & 15) * 64;
        const int n  = nh >> 4;
        const int h  = nh & 15;

        const int la = l0 + wave * 16 + m;
        const float* xr = x + (size_t)(n * 16384 + la * 16 + h) * 64;
        float4 f0 = *(const float4*)(xr + q4 * 8);
        float4 f1 = *(const float4*)(xr + q4 * 8 + 4);
        float4 f2 = *(const float4*)(xr + 32 + q4 * 8);
        float4 f3 = *(const float4*)(xr + 32 + q4 * 8 + 4);
        bf16x8 a0 = cvt8(f0, f1);
        bf16x8 a1 = cvt8(f2, f3);

        floatx4 acc[4];
        #pragma unroll
        for (int sub = 0; sub < 4; ++sub) {
            bf16x8 b0 = load8bf(&wl[sub * 16 + m][q4 * 8]);
            bf16x8 b1 = load8bf(&wl[sub * 16 + m][32 + q4 * 8]);
            floatx4 z = {0.f, 0.f, 0.f, 0.f};
            z = __builtin_amdgcn_mfma_f32_16x16x32_bf16(a0, b0, z, 0, 0, 0);
            z = __builtin_amdgcn_mfma_f32_16x16x32_bf16(a1, b1, z, 0, 0, 0);
            acc[sub] = z;
        }

        #pragma unroll
        for (int sub = 0; sub < 4; ++sub) {
            #pragma unroll
            for (int r = 0; r < 4; r += 2) {
                PkU u; u.h[0] = (bf16_t)acc[sub][r]; u.h[1] = (bf16_t)acc[sub][r + 1];
                *(unsigned*)&lo[sub * 16 + m][wave * 16 + q4 * 4 + r] = u.u;
            }
        }
        __syncthreads();

        const int e  = threadIdx.x >> 2;
        const int lc = (threadIdx.x & 3) * 16;
        bf16_t* dst = vt + ((size_t)nh * 64 + e) * 1024 + l0 + lc;
        *(bf16x8*)dst       = *(const bf16x8*)&lo[e][lc];
        *(bf16x8*)(dst + 8) = *(const bf16x8*)&lo[e][lc + 8];
    } else {
        const int row0 = blockIdx.x * 64 + wave * 16;

        const float* xr = x + (size_t)(row0 + m) * 64;
        float4 f0 = *(const float4*)(xr + q4 * 8);
        float4 f1 = *(const float4*)(xr + q4 * 8 + 4);
        float4 f2 = *(const float4*)(xr + 32 + q4 * 8);
        float4 f3 = *(const float4*)(xr + 32 + q4 * 8 + 4);
        bf16x8 a0 = cvt8(f0, f1);
        bf16x8 a1 = cvt8(f2, f3);

        floatx4 acc[4];
        #pragma unroll
        for (int sub = 0; sub < 4; ++sub) {
            bf16x8 b0 = load8bf(&wl[sub * 16 + m][q4 * 8]);
            bf16x8 b1 = load8bf(&wl[sub * 16 + m][32 + q4 * 8]);
            floatx4 z = {0.f, 0.f, 0.f, 0.f};
            z = __builtin_amdgcn_mfma_f32_16x16x32_bf16(a0, b0, z, 0, 0, 0);
            z = __builtin_amdgcn_mfma_f32_16x16x32_bf16(a1, b1, z, 0, 0, 0);
            acc[sub] = z;
        }

        #pragma unroll
        for (int r = 0; r < 4; ++r) {
            const int g = row0 + q4 * 4 + r;
            const int n = g >> 14;
            const int l = (g >> 4) & 1023;
            const int h = g & 15;
            const int nh = n * 16 + h;
            #pragma unroll
            for (int sub = 0; sub < 4; ++sub) {
                const int e = sub * 16 + m;
                const bf16_t val = (bf16_t)acc[sub][r];
                if (op == 0) {
                    qp[((size_t)nh * 1024 + l) * 64 + e] = val;
                } else {
                    kp[((size_t)nh * 1024 + l) * 64 + e] = val;
                }
            }
        }
    }
}

// ---------------------------------------------------------------------------
// Kernel 2: flash attention, LDS-staged double-buffered K/V (2-phase pipeline).
// Identical to round 3 EXCEPT: __launch_bounds__(256) with NO min-waves arg.
// (256,4) drove the allocator to 64 VGPRs -> ~1GB scratch spill traffic
// (WRITE_SIZE 16->595MB). Plain bound restores VGPR~110, zero spill.
// ---------------------------------------------------------------------------
__global__ __launch_bounds__(256) void attn_kernel(
    bf16_t* __restrict__ qp, const bf16_t* __restrict__ kp,
    const bf16_t* __restrict__ vt)
{
    __shared__ __align__(16) bf16_t kl[2][64][64];
    __shared__ __align__(16) bf16_t vl[2][64][64];

    const int lane = threadIdx.x & 63;
    const int wave = threadIdx.x >> 6;
    const int m  = lane & 15;
    const int q4 = lane >> 4;

    const int nh   = blockIdx.x & 127;   // same-nh blocks -> same XCD
    const int qblk = blockIdx.x >> 7;

    bf16_t* Q = qp + (size_t)nh * 65536;
    const bf16_t* K = kp + (size_t)nh * 65536;
    const bf16_t* V = vt + (size_t)nh * 65536;   // [D][L]

    const int qb0 = qblk * 128 + wave * 32;
    const int qb1 = qb0 + 16;

    // staging lane decomposition: lane -> (row-in-8-group, 16B slot)
    const int srow  = lane >> 3;         // 0..7
    const int sslot = lane & 7;          // 0..7
    const int ch    = sslot ^ srow;      // pre-swizzled global chunk

    auto stage = [&](int b, int kb) {
        #pragma unroll
        for (int i = 0; i < 2; ++i) {
            const int rbase = wave * 16 + i * 8;
            const int row   = rbase + srow;
            __builtin_amdgcn_global_load_lds(
                (const __attribute__((address_space(1))) unsigned int*)(K + (size_t)(kb + row) * 64 + ch * 8),
                (__attribute__((address_space(3))) unsigned int*)(&kl[b][rbase][0]),
                16, 0, 0);
            __builtin_amdgcn_global_load_lds(
                (const __attribute__((address_space(1))) unsigned int*)(V + (size_t)row * 1024 + kb + ch * 8),
                (__attribute__((address_space(3))) unsigned int*)(&vl[b][rbase][0]),
                16, 0, 0);
        }
    };

    stage(0, 0);   // prologue: tile 0 in flight

    bf16x8 bq0a = load8bf(Q + (qb0 + m) * 64 + q4 * 8);
    bf16x8 bq0b = load8bf(Q + (qb0 + m) * 64 + 32 + q4 * 8);
    bf16x8 bq1a = load8bf(Q + (qb1 + m) * 64 + q4 * 8);
    bf16x8 bq1b = load8bf(Q + (qb1 + m) * 64 + 32 + q4 * 8);

    floatx4 o0[4], o1[4];
    #pragma unroll
    for (int i = 0; i < 4; ++i) {
        o0[i] = (floatx4){0.f, 0.f, 0.f, 0.f};
        o1[i] = (floatx4){0.f, 0.f, 0.f, 0.f};
    }
    float l0 = 0.f, l1 = 0.f;
    const float CE = 1.4426950408889634f * 0.03125f;   // log2(e)/sqrt(1024)

    // per-lane swizzled fragment column offsets (elements)
    const int c0 = (q4 ^ (m & 7)) * 8;
    const int c1 = ((q4 + 4) ^ (m & 7)) * 8;

    int cur = 0;
    __syncthreads();   // drains prologue stage + barrier

    for (int kt = 0; kt < 16; ++kt) {
        if (kt < 15) stage(cur ^ 1, (kt + 1) * 64);   // next tile under compute

        // S^T[key][q] from LDS K
        floatx4 s0[4], s1[4];
        __builtin_amdgcn_s_setprio(1);
        #pragma unroll
        for (int sk = 0; sk < 4; ++sk) {
            bf16x8 ka0 = load8bf(&kl[cur][sk * 16 + m][c0]);
            bf16x8 ka1 = load8bf(&kl[cur][sk * 16 + m][c1]);
            floatx4 z = {0.f, 0.f, 0.f, 0.f};
            z = __builtin_amdgcn_mfma_f32_16x16x32_bf16(ka0, bq0a, z, 0, 0, 0);
            z = __builtin_amdgcn_mfma_f32_16x16x32_bf16(ka1, bq0b, z, 0, 0, 0);
            s0[sk] = z;
            floatx4 y = {0.f, 0.f, 0.f, 0.f};
            y = __builtin_amdgcn_mfma_f32_16x16x32_bf16(ka0, bq1a, y, 0, 0, 0);
            y = __builtin_amdgcn_mfma_f32_16x16x32_bf16(ka1, bq1b, y, 0, 0, 0);
            s1[sk] = y;
        }
        __builtin_amdgcn_s_setprio(0);

        // p = exp2(s*CE); per-lane l accumulation
        unsigned pk0[2][4], pk1[2][4];
        #pragma unroll
        for (int c = 0; c < 2; ++c) {
            #pragma unroll
            for (int r = 0; r < 4; ++r) {
                float a0 = exp2f(s0[2 * c][r] * CE);
                float a1 = exp2f(s0[2 * c + 1][r] * CE);
                l0 += a0 + a1;
                PkU u; u.h[0] = (bf16_t)a0; u.h[1] = (bf16_t)a1;
                pk0[c][r] = u.u;
                float b0 = exp2f(s1[2 * c][r] * CE);
                float b1 = exp2f(s1[2 * c + 1][r] * CE);
                l1 += b0 + b1;
                PkU v; v.h[0] = (bf16_t)b0; v.h[1] = (bf16_t)b1;
                pk1[c][r] = v.u;
            }
        }

        // V fragments from LDS, issued before the transpose so ds_read
        // latency hides under the 32 bpermutes
        bf16x8 va[8];
        #pragma unroll
        for (int sd = 0; sd < 4; ++sd) {
            va[2 * sd]     = load8bf(&vl[cur][sd * 16 + m][c0]);
            va[2 * sd + 1] = load8bf(&vl[cur][sd * 16 + m][c1]);
        }

        // in-register transpose (verified element-wise, unchanged)
        bf16x8 bp0[2], bp1[2];
        const int hsel = q4 >> 1;
        #pragma unroll
        for (int c = 0; c < 2; ++c) {
            #pragma unroll
            for (int j = 0; j < 8; ++j) {
                const int src = m + 16 * ((2 * q4 + (j >> 2)) & 3);
                PkU u; u.u = (unsigned)__shfl((int)pk0[c][j & 3], src, 64);
                bp0[c][j] = u.h[hsel];
                PkU v; v.u = (unsigned)__shfl((int)pk1[c][j & 3], src, 64);
                bp1[c][j] = v.h[hsel];
            }
        }

        // O^T[d][q] += V^T-frag x P-frag
        __builtin_amdgcn_s_setprio(1);
        #pragma unroll
        for (int sd = 0; sd < 4; ++sd) {
            o0[sd] = __builtin_amdgcn_mfma_f32_16x16x32_bf16(va[2 * sd],     bp0[0], o0[sd], 0, 0, 0);
            o0[sd] = __builtin_amdgcn_mfma_f32_16x16x32_bf16(va[2 * sd + 1], bp0[1], o0[sd], 0, 0, 0);
            o1[sd] = __builtin_amdgcn_mfma_f32_16x16x32_bf16(va[2 * sd],     bp1[0], o1[sd], 0, 0, 0);
            o1[sd] = __builtin_amdgcn_mfma_f32_16x16x32_bf16(va[2 * sd + 1], bp1[1], o1[sd], 0, 0, 0);
        }
        __builtin_amdgcn_s_setprio(0);

        __syncthreads();   // stage(cur^1) complete + all reads of cur done
        cur ^= 1;
    }

    // final l reduction
    l0 += __shfl_xor(l0, 16, 64); l0 += __shfl_xor(l0, 32, 64);
    l1 += __shfl_xor(l1, 16, 64); l1 += __shfl_xor(l1, 32, 64);
    const float i0 = 1.0f / l0, i1 = 1.0f / l1;

    #pragma unroll
    for (int sd = 0; sd < 4; ++sd) {
        bf16x4 w0, w1;
        #pragma unroll
        for (int r = 0; r < 4; ++r) {
            w0[r] = (bf16_t)(o0[sd][r] * i0);
            w1[r] = (bf16_t)(o1[sd][r] * i1);
        }
        *(bf16x4*)(Q + (size_t)(qb0 + m) * 64 + sd * 16 + q4 * 4) = w0;
        *(bf16x4*)(Q + (size_t)(qb1 + m) * 64 + sd * 16 + q4 * 4) = w1;
    }
}

// ---------------------------------------------------------------------------
// Kernel 3: out(fp32) = AO @ Wo^T. BYTE-IDENTICAL to the round-0 PASSING
// version.
// ---------------------------------------------------------------------------
__global__ __launch_bounds__(256) void outproj_kernel(
    const bf16_t* __restrict__ aoq, const float* __restrict__ Wo,
    float* __restrict__ out)
{
    __shared__ __align__(16) bf16_t wl[64][72];

    const int wave = threadIdx.x >> 6;
    const int lane = threadIdx.x & 63;
    const int m  = lane & 15;
    const int q4 = lane >> 4;

    const int row0 = blockIdx.x * 64 + wave * 16;
    const int col0 = blockIdx.y * 64;

    const int ga = row0 + m;
    const int n_a = ga >> 10;
    const int q_a = ga & 1023;

    const int ts_f  = threadIdx.x >> 2;
    const int ts_kg = (threadIdx.x & 3) * 16;

    floatx4 acc[4];
    #pragma unroll
    for (int i = 0; i < 4; ++i) acc[i] = (floatx4){0.f, 0.f, 0.f, 0.f};

    for (int kc = 0; kc < 1024; kc += 64) {
        __syncthreads();
        #pragma unroll
        for (int j = 0; j < 4; ++j) {
            float4 v = *(const float4*)(Wo + (size_t)(col0 + ts_f) * 1024 + kc + ts_kg + j * 4);
            *(bf16x4*)&wl[ts_f][ts_kg + j * 4] = cvt4(v);
        }
        __syncthreads();

        const int h = kc >> 6;
        const bf16_t* arow = aoq + ((size_t)(n_a * 16 + h) * 1024 + q_a) * 64;
        bf16x8 a0 = load8bf(arow + q4 * 8);
        bf16x8 a1 = load8bf(arow + 32 + q4 * 8);
        #pragma unroll
        for (int sub = 0; sub < 4; ++sub) {
            bf16x8 b0 = load8bf(&wl[sub * 16 + m][q4 * 8]);
            bf16x8 b1 = load8bf(&wl[sub * 16 + m][32 + q4 * 8]);
            acc[sub] = __builtin_amdgcn_mfma_f32_16x16x32_bf16(a0, b0, acc[sub], 0, 0, 0);
            acc[sub] = __builtin_amdgcn_mfma_f32_16x16x32_bf16(a1, b1, acc[sub], 0, 0, 0);
        }
    }

    #pragma unroll
    for (int r = 0; r < 4; ++r) {
        const int g = row0 + q4 * 4 + r;
        #pragma unroll
        for (int sub = 0; sub < 4; ++sub)
            out[(size_t)g * 1024 + col0 + sub * 16 + m] = acc[sub][r];
    }
}

// ---------------------------------------------------------------------------
extern "C" void kernel_launch(void* const* d_in, const int* in_sizes, int n_in,
                              void* d_out, int out_size, void* d_ws, size_t ws_size,
                              hipStream_t stream) {
    const float* key   = (const float*)d_in[0];
    const float* query = (const float*)d_in[1];
    const float* value = (const float*)d_in[2];
    // d_in[3] = mask — faithfully ignored per the reference
    const float* Wq = (const float*)d_in[4];
    const float* Wk = (const float*)d_in[5];
    const float* Wv = (const float*)d_in[6];
    const float* Wo = (const float*)d_in[7];

    const size_t TENS = (size_t)NB * SEQ * EMB;   // 8388608
    bf16_t* qp = (bf16_t*)d_ws;                   // [N*H][L][D]; becomes AO in-place
    bf16_t* vt = qp + TENS;                       // [N*H][D][L]
    bf16_t* kp = (bf16_t*)d_out;                  // staged in d_out, dead before outproj

    hipLaunchKernelGGL(proj_kernel, dim3(2048, 3), dim3(256), 0, stream,
                       query, key, value, Wq, Wk, Wv, qp, kp, vt);
    hipLaunchKernelGGL(attn_kernel, dim3(1024), dim3(256), 0, stream, qp, kp, vt);
    hipLaunchKernelGGL(outproj_kernel, dim3(128, 16), dim3(256), 0, stream,
                       qp, Wo, (float*)d_out);
}

// Round 5
// 322.123 us; speedup vs baseline: 1.4316x; 1.0355x over previous
//
#include <hip/hip_runtime.h>
#include <hip/hip_bf16.h>

#define HEADS 16
#define HDIM  64
#define EMB   1024
#define NB    8
#define SEQ   1024

typedef __bf16 bf16_t;
typedef __bf16 bf16x8 __attribute__((ext_vector_type(8)));
typedef __bf16 bf16x4 __attribute__((ext_vector_type(4)));
typedef float  floatx4 __attribute__((ext_vector_type(4)));

union PkU { unsigned u; __bf16 h[2]; };

__device__ __forceinline__ bf16x8 load8bf(const bf16_t* p) { return *(const bf16x8*)p; }
__device__ __forceinline__ bf16x4 cvt4(float4 a) {
    bf16x4 r; r[0]=(bf16_t)a.x; r[1]=(bf16_t)a.y; r[2]=(bf16_t)a.z; r[3]=(bf16_t)a.w;
    return r;
}
__device__ __forceinline__ bf16x8 cvt8(float4 a, float4 b) {
    bf16x8 r;
    r[0]=(bf16_t)a.x; r[1]=(bf16_t)a.y; r[2]=(bf16_t)a.z; r[3]=(bf16_t)a.w;
    r[4]=(bf16_t)b.x; r[5]=(bf16_t)b.y; r[6]=(bf16_t)b.z; r[7]=(bf16_t)b.w;
    return r;
}

// ---------------------------------------------------------------------------
// Kernel 1: per-head projections (byte-identical to round-4 passing version).
// ---------------------------------------------------------------------------
__global__ __launch_bounds__(256) void proj_kernel(
    const float* __restrict__ q_in, const float* __restrict__ k_in,
    const float* __restrict__ v_in,
    const float* __restrict__ Wq, const float* __restrict__ Wk,
    const float* __restrict__ Wv,
    bf16_t* __restrict__ qp, bf16_t* __restrict__ kp, bf16_t* __restrict__ vt)
{
    __shared__ __align__(16) bf16_t wl[64][72];
    __shared__ __align__(16) bf16_t lo[64][72];   // op2 transpose staging

    const int wave = threadIdx.x >> 6;
    const int lane = threadIdx.x & 63;
    const int m  = lane & 15;
    const int q4 = lane >> 4;
    const int op = blockIdx.y;

    const float* x = (op == 0) ? q_in : (op == 1) ? k_in : v_in;
    const float* W = (op == 0) ? Wq   : (op == 1) ? Wk   : Wv;

    {
        const int t  = threadIdx.x;
        const int f  = t >> 2;
        const int kg = (t & 3) * 16;
        #pragma unroll
        for (int j = 0; j < 4; ++j) {
            float4 v = *(const float4*)(W + f * 64 + kg + j * 4);
            *(bf16x4*)&wl[f][kg + j * 4] = cvt4(v);
        }
    }
    __syncthreads();

    if (op == 2) {
        const int nh = blockIdx.x >> 4;          // 0..127
        const int l0 = (blockIdx.x & 15) * 64;
        const int n  = nh >> 4;
        const int h  = nh & 15;

        const int la = l0 + wave * 16 + m;
        const float* xr = x + (size_t)(n * 16384 + la * 16 + h) * 64;
        float4 f0 = *(const float4*)(xr + q4 * 8);
        float4 f1 = *(const float4*)(xr + q4 * 8 + 4);
        float4 f2 = *(const float4*)(xr + 32 + q4 * 8);
        float4 f3 = *(const float4*)(xr + 32 + q4 * 8 + 4);
        bf16x8 a0 = cvt8(f0, f1);
        bf16x8 a1 = cvt8(f2, f3);

        floatx4 acc[4];
        #pragma unroll
        for (int sub = 0; sub < 4; ++sub) {
            bf16x8 b0 = load8bf(&wl[sub * 16 + m][q4 * 8]);
            bf16x8 b1 = load8bf(&wl[sub * 16 + m][32 + q4 * 8]);
            floatx4 z = {0.f, 0.f, 0.f, 0.f};
            z = __builtin_amdgcn_mfma_f32_16x16x32_bf16(a0, b0, z, 0, 0, 0);
            z = __builtin_amdgcn_mfma_f32_16x16x32_bf16(a1, b1, z, 0, 0, 0);
            acc[sub] = z;
        }

        #pragma unroll
        for (int sub = 0; sub < 4; ++sub) {
            #pragma unroll
            for (int r = 0; r < 4; r += 2) {
                PkU u; u.h[0] = (bf16_t)acc[sub][r]; u.h[1] = (bf16_t)acc[sub][r + 1];
                *(unsigned*)&lo[sub * 16 + m][wave * 16 + q4 * 4 + r] = u.u;
            }
        }
        __syncthreads();

        const int e  = threadIdx.x >> 2;
        const int lc = (threadIdx.x & 3) * 16;
        bf16_t* dst = vt + ((size_t)nh * 64 + e) * 1024 + l0 + lc;
        *(bf16x8*)dst       = *(const bf16x8*)&lo[e][lc];
        *(bf16x8*)(dst + 8) = *(const bf16x8*)&lo[e][lc + 8];
    } else {
        const int row0 = blockIdx.x * 64 + wave * 16;

        const float* xr = x + (size_t)(row0 + m) * 64;
        float4 f0 = *(const float4*)(xr + q4 * 8);
        float4 f1 = *(const float4*)(xr + q4 * 8 + 4);
        float4 f2 = *(const float4*)(xr + 32 + q4 * 8);
        float4 f3 = *(const float4*)(xr + 32 + q4 * 8 + 4);
        bf16x8 a0 = cvt8(f0, f1);
        bf16x8 a1 = cvt8(f2, f3);

        floatx4 acc[4];
        #pragma unroll
        for (int sub = 0; sub < 4; ++sub) {
            bf16x8 b0 = load8bf(&wl[sub * 16 + m][q4 * 8]);
            bf16x8 b1 = load8bf(&wl[sub * 16 + m][32 + q4 * 8]);
            floatx4 z = {0.f, 0.f, 0.f, 0.f};
            z = __builtin_amdgcn_mfma_f32_16x16x32_bf16(a0, b0, z, 0, 0, 0);
            z = __builtin_amdgcn_mfma_f32_16x16x32_bf16(a1, b1, z, 0, 0, 0);
            acc[sub] = z;
        }

        #pragma unroll
        for (int r = 0; r < 4; ++r) {
            const int g = row0 + q4 * 4 + r;
            const int n = g >> 14;
            const int l = (g >> 4) & 1023;
            const int h = g & 15;
            const int nh = n * 16 + h;
            #pragma unroll
            for (int sub = 0; sub < 4; ++sub) {
                const int e = sub * 16 + m;
                const bf16_t val = (bf16_t)acc[sub][r];
                if (op == 0) {
                    qp[((size_t)nh * 1024 + l) * 64 + e] = val;
                } else {
                    kp[((size_t)nh * 1024 + l) * 64 + e] = val;
                }
            }
        }
    }
}

// ---------------------------------------------------------------------------
// Kernel 2: flash attention. Round-5 change: SINGLE q-tile per wave, grid
// 1024 -> 2048 blocks (qblk 0..15, 64 queries per block). Rationale: r4
// counters (Mfma 10%, VALU 35%, HBM 4.7%, occ 20%) = latency-bound with only
// 4 blocks/CU (grid-capped). Halving block granularity doubles independent
// blocks/CU (LDS 32KB -> 5 resident), drops per-wave VGPR, same total math.
// Staging/swizzle/transpose logic byte-equivalent per tile.
// ---------------------------------------------------------------------------
__global__ __launch_bounds__(256) void attn_kernel(
    bf16_t* __restrict__ qp, const bf16_t* __restrict__ kp,
    const bf16_t* __restrict__ vt)
{
    __shared__ __align__(16) bf16_t kl[2][64][64];
    __shared__ __align__(16) bf16_t vl[2][64][64];

    const int lane = threadIdx.x & 63;
    const int wave = threadIdx.x >> 6;
    const int m  = lane & 15;
    const int q4 = lane >> 4;

    const int nh   = blockIdx.x & 127;   // same-nh blocks -> same XCD
    const int qblk = blockIdx.x >> 7;    // 0..15

    bf16_t* Q = qp + (size_t)nh * 65536;
    const bf16_t* K = kp + (size_t)nh * 65536;
    const bf16_t* V = vt + (size_t)nh * 65536;   // [D][L]

    const int qb = qblk * 64 + wave * 16;        // this wave's 16 queries

    // staging lane decomposition: lane -> (row-in-8-group, 16B slot)
    const int srow  = lane >> 3;         // 0..7
    const int sslot = lane & 7;          // 0..7
    const int ch    = sslot ^ srow;      // pre-swizzled global chunk

    auto stage = [&](int b, int kb) {
        #pragma unroll
        for (int i = 0; i < 2; ++i) {
            const int rbase = wave * 16 + i * 8;
            const int row   = rbase + srow;
            __builtin_amdgcn_global_load_lds(
                (const __attribute__((address_space(1))) unsigned int*)(K + (size_t)(kb + row) * 64 + ch * 8),
                (__attribute__((address_space(3))) unsigned int*)(&kl[b][rbase][0]),
                16, 0, 0);
            __builtin_amdgcn_global_load_lds(
                (const __attribute__((address_space(1))) unsigned int*)(V + (size_t)row * 1024 + kb + ch * 8),
                (__attribute__((address_space(3))) unsigned int*)(&vl[b][rbase][0]),
                16, 0, 0);
        }
    };

    stage(0, 0);   // prologue: tile 0 in flight

    bf16x8 bqa = load8bf(Q + (qb + m) * 64 + q4 * 8);
    bf16x8 bqb = load8bf(Q + (qb + m) * 64 + 32 + q4 * 8);

    floatx4 o[4];
    #pragma unroll
    for (int i = 0; i < 4; ++i) o[i] = (floatx4){0.f, 0.f, 0.f, 0.f};
    float lsum = 0.f;
    const float CE = 1.4426950408889634f * 0.03125f;   // log2(e)/sqrt(1024)

    // per-lane swizzled fragment column offsets (elements)
    const int c0 = (q4 ^ (m & 7)) * 8;
    const int c1 = ((q4 + 4) ^ (m & 7)) * 8;
    const int hsel = q4 >> 1;

    int cur = 0;
    __syncthreads();   // drains prologue stage + barrier

    for (int kt = 0; kt < 16; ++kt) {
        if (kt < 15) stage(cur ^ 1, (kt + 1) * 64);   // next tile under compute

        // S^T[key][q] from LDS K
        floatx4 s[4];
        __builtin_amdgcn_s_setprio(1);
        #pragma unroll
        for (int sk = 0; sk < 4; ++sk) {
            bf16x8 ka0 = load8bf(&kl[cur][sk * 16 + m][c0]);
            bf16x8 ka1 = load8bf(&kl[cur][sk * 16 + m][c1]);
            floatx4 z = {0.f, 0.f, 0.f, 0.f};
            z = __builtin_amdgcn_mfma_f32_16x16x32_bf16(ka0, bqa, z, 0, 0, 0);
            z = __builtin_amdgcn_mfma_f32_16x16x32_bf16(ka1, bqb, z, 0, 0, 0);
            s[sk] = z;
        }
        __builtin_amdgcn_s_setprio(0);

        // p = exp2(s*CE); pack (sk=2c, sk=2c+1) pairs as bf16x2
        unsigned pk[2][4];
        #pragma unroll
        for (int c = 0; c < 2; ++c) {
            #pragma unroll
            for (int r = 0; r < 4; ++r) {
                float a0 = exp2f(s[2 * c][r] * CE);
                float a1 = exp2f(s[2 * c + 1][r] * CE);
                lsum += a0 + a1;
                PkU u; u.h[0] = (bf16_t)a0; u.h[1] = (bf16_t)a1;
                pk[c][r] = u.u;
            }
        }

        // V fragments from LDS, issued before the transpose so ds_read
        // latency hides under the bpermutes
        bf16x8 va[8];
        #pragma unroll
        for (int sd = 0; sd < 4; ++sd) {
            va[2 * sd]     = load8bf(&vl[cur][sd * 16 + m][c0]);
            va[2 * sd + 1] = load8bf(&vl[cur][sd * 16 + m][c1]);
        }

        // in-register transpose (verified element-wise, single tile)
        bf16x8 bp[2];
        #pragma unroll
        for (int c = 0; c < 2; ++c) {
            #pragma unroll
            for (int j = 0; j < 8; ++j) {
                const int src = m + 16 * ((2 * q4 + (j >> 2)) & 3);
                PkU u; u.u = (unsigned)__shfl((int)pk[c][j & 3], src, 64);
                bp[c][j] = u.h[hsel];
            }
        }

        // O^T[d][q] += V^T-frag x P-frag
        __builtin_amdgcn_s_setprio(1);
        #pragma unroll
        for (int sd = 0; sd < 4; ++sd) {
            o[sd] = __builtin_amdgcn_mfma_f32_16x16x32_bf16(va[2 * sd],     bp[0], o[sd], 0, 0, 0);
            o[sd] = __builtin_amdgcn_mfma_f32_16x16x32_bf16(va[2 * sd + 1], bp[1], o[sd], 0, 0, 0);
        }
        __builtin_amdgcn_s_setprio(0);

        __syncthreads();   // stage(cur^1) complete + all reads of cur done
        cur ^= 1;
    }

    // final l reduction: keys spread across the 4 q4-groups only
    lsum += __shfl_xor(lsum, 16, 64); lsum += __shfl_xor(lsum, 32, 64);
    const float inv = 1.0f / lsum;

    #pragma unroll
    for (int sd = 0; sd < 4; ++sd) {
        bf16x4 w;
        #pragma unroll
        for (int r = 0; r < 4; ++r) w[r] = (bf16_t)(o[sd][r] * inv);
        *(bf16x4*)(Q + (size_t)(qb + m) * 64 + sd * 16 + q4 * 4) = w;
    }
}

// ---------------------------------------------------------------------------
// Kernel 3: out(fp32) = AO @ Wo^T. BYTE-IDENTICAL to the round-0/4 PASSING
// version.
// ---------------------------------------------------------------------------
__global__ __launch_bounds__(256) void outproj_kernel(
    const bf16_t* __restrict__ aoq, const float* __restrict__ Wo,
    float* __restrict__ out)
{
    __shared__ __align__(16) bf16_t wl[64][72];

    const int wave = threadIdx.x >> 6;
    const int lane = threadIdx.x & 63;
    const int m  = lane & 15;
    const int q4 = lane >> 4;

    const int row0 = blockIdx.x * 64 + wave * 16;
    const int col0 = blockIdx.y * 64;

    const int ga = row0 + m;
    const int n_a = ga >> 10;
    const int q_a = ga & 1023;

    const int ts_f  = threadIdx.x >> 2;
    const int ts_kg = (threadIdx.x & 3) * 16;

    floatx4 acc[4];
    #pragma unroll
    for (int i = 0; i < 4; ++i) acc[i] = (floatx4){0.f, 0.f, 0.f, 0.f};

    for (int kc = 0; kc < 1024; kc += 64) {
        __syncthreads();
        #pragma unroll
        for (int j = 0; j < 4; ++j) {
            float4 v = *(const float4*)(Wo + (size_t)(col0 + ts_f) * 1024 + kc + ts_kg + j * 4);
            *(bf16x4*)&wl[ts_f][ts_kg + j * 4] = cvt4(v);
        }
        __syncthreads();

        const int h = kc >> 6;
        const bf16_t* arow = aoq + ((size_t)(n_a * 16 + h) * 1024 + q_a) * 64;
        bf16x8 a0 = load8bf(arow + q4 * 8);
        bf16x8 a1 = load8bf(arow + 32 + q4 * 8);
        #pragma unroll
        for (int sub = 0; sub < 4; ++sub) {
            bf16x8 b0 = load8bf(&wl[sub * 16 + m][q4 * 8]);
            bf16x8 b1 = load8bf(&wl[sub * 16 + m][32 + q4 * 8]);
            acc[sub] = __builtin_amdgcn_mfma_f32_16x16x32_bf16(a0, b0, acc[sub], 0, 0, 0);
            acc[sub] = __builtin_amdgcn_mfma_f32_16x16x32_bf16(a1, b1, acc[sub], 0, 0, 0);
        }
    }

    #pragma unroll
    for (int r = 0; r < 4; ++r) {
        const int g = row0 + q4 * 4 + r;
        #pragma unroll
        for (int sub = 0; sub < 4; ++sub)
            out[(size_t)g * 1024 + col0 + sub * 16 + m] = acc[sub][r];
    }
}

// ---------------------------------------------------------------------------
extern "C" void kernel_launch(void* const* d_in, const int* in_sizes, int n_in,
                              void* d_out, int out_size, void* d_ws, size_t ws_size,
                              hipStream_t stream) {
    const float* key   = (const float*)d_in[0];
    const float* query = (const float*)d_in[1];
    const float* value = (const float*)d_in[2];
    // d_in[3] = mask — faithfully ignored per the reference
    const float* Wq = (const float*)d_in[4];
    const float* Wk = (const float*)d_in[5];
    const float* Wv = (const float*)d_in[6];
    const float* Wo = (const float*)d_in[7];

    const size_t TENS = (size_t)NB * SEQ * EMB;   // 8388608
    bf16_t* qp = (bf16_t*)d_ws;                   // [N*H][L][D]; becomes AO in-place
    bf16_t* vt = qp + TENS;                       // [N*H][D][L]
    bf16_t* kp = (bf16_t*)d_out;                  // staged in d_out, dead before outproj

    hipLaunchKernelGGL(proj_kernel, dim3(2048, 3), dim3(256), 0, stream,
                       query, key, value, Wq, Wk, Wv, qp, kp, vt);
    hipLaunchKernelGGL(attn_kernel, dim3(2048), dim3(256), 0, stream, qp, kp, vt);
    hipLaunchKernelGGL(outproj_kernel, dim3(128, 16), dim3(256), 0, stream,
                       qp, Wo, (float*)d_out);
}

// Round 6
// 300.973 us; speedup vs baseline: 1.5322x; 1.0703x over previous
//
#include <hip/hip_runtime.h>
#include <hip/hip_bf16.h>

#define HEADS 16
#define HDIM  64
#define EMB   1024
#define NB    8
#define SEQ   1024

typedef __bf16 bf16_t;
typedef __bf16 bf16x8 __attribute__((ext_vector_type(8)));
typedef __bf16 bf16x4 __attribute__((ext_vector_type(4)));
typedef float  floatx4 __attribute__((ext_vector_type(4)));

union PkU { unsigned u; __bf16 h[2]; };

__device__ __forceinline__ bf16x8 load8bf(const bf16_t* p) { return *(const bf16x8*)p; }
__device__ __forceinline__ bf16x4 cvt4(float4 a) {
    bf16x4 r; r[0]=(bf16_t)a.x; r[1]=(bf16_t)a.y; r[2]=(bf16_t)a.z; r[3]=(bf16_t)a.w;
    return r;
}
__device__ __forceinline__ bf16x8 cvt8(float4 a, float4 b) {
    bf16x8 r;
    r[0]=(bf16_t)a.x; r[1]=(bf16_t)a.y; r[2]=(bf16_t)a.z; r[3]=(bf16_t)a.w;
    r[4]=(bf16_t)b.x; r[5]=(bf16_t)b.y; r[6]=(bf16_t)b.z; r[7]=(bf16_t)b.w;
    return r;
}

// ---------------------------------------------------------------------------
// Kernel 1: per-head projections. Round-6 change: Q/K epilogue now stages the
// 64x64 tile in LDS (mirror of the validated op2/V path) and stores full
// 128B rows as 2x bf16x8 per thread, replacing 16 scalar 2B global stores
// per thread (8x fewer store instructions, full-line writes).
// ---------------------------------------------------------------------------
__global__ __launch_bounds__(256) void proj_kernel(
    const float* __restrict__ q_in, const float* __restrict__ k_in,
    const float* __restrict__ v_in,
    const float* __restrict__ Wq, const float* __restrict__ Wk,
    const float* __restrict__ Wv,
    bf16_t* __restrict__ qp, bf16_t* __restrict__ kp, bf16_t* __restrict__ vt)
{
    __shared__ __align__(16) bf16_t wl[64][72];
    __shared__ __align__(16) bf16_t lo[64][72];   // output staging

    const int wave = threadIdx.x >> 6;
    const int lane = threadIdx.x & 63;
    const int m  = lane & 15;
    const int q4 = lane >> 4;
    const int op = blockIdx.y;

    const float* x = (op == 0) ? q_in : (op == 1) ? k_in : v_in;
    const float* W = (op == 0) ? Wq   : (op == 1) ? Wk   : Wv;

    {
        const int t  = threadIdx.x;
        const int f  = t >> 2;
        const int kg = (t & 3) * 16;
        #pragma unroll
        for (int j = 0; j < 4; ++j) {
            float4 v = *(const float4*)(W + f * 64 + kg + j * 4);
            *(bf16x4*)&wl[f][kg + j * 4] = cvt4(v);
        }
    }
    __syncthreads();

    if (op == 2) {
        const int nh = blockIdx.x >> 4;          // 0..127
        const int l0 = (blockIdx.x & 15) * 64;
        const int n  = nh >> 4;
        const int h  = nh & 15;

        const int la = l0 + wave * 16 + m;
        const float* xr = x + (size_t)(n * 16384 + la * 16 + h) * 64;
        float4 f0 = *(const float4*)(xr + q4 * 8);
        float4 f1 = *(const float4*)(xr + q4 * 8 + 4);
        float4 f2 = *(const float4*)(xr + 32 + q4 * 8);
        float4 f3 = *(const float4*)(xr + 32 + q4 * 8 + 4);
        bf16x8 a0 = cvt8(f0, f1);
        bf16x8 a1 = cvt8(f2, f3);

        floatx4 acc[4];
        #pragma unroll
        for (int sub = 0; sub < 4; ++sub) {
            bf16x8 b0 = load8bf(&wl[sub * 16 + m][q4 * 8]);
            bf16x8 b1 = load8bf(&wl[sub * 16 + m][32 + q4 * 8]);
            floatx4 z = {0.f, 0.f, 0.f, 0.f};
            z = __builtin_amdgcn_mfma_f32_16x16x32_bf16(a0, b0, z, 0, 0, 0);
            z = __builtin_amdgcn_mfma_f32_16x16x32_bf16(a1, b1, z, 0, 0, 0);
            acc[sub] = z;
        }

        // stage transposed tile: lo[e][l_local]
        #pragma unroll
        for (int sub = 0; sub < 4; ++sub) {
            #pragma unroll
            for (int r = 0; r < 4; r += 2) {
                PkU u; u.h[0] = (bf16_t)acc[sub][r]; u.h[1] = (bf16_t)acc[sub][r + 1];
                *(unsigned*)&lo[sub * 16 + m][wave * 16 + q4 * 4 + r] = u.u;
            }
        }
        __syncthreads();

        const int e  = threadIdx.x >> 2;
        const int lc = (threadIdx.x & 3) * 16;
        bf16_t* dst = vt + ((size_t)nh * 64 + e) * 1024 + l0 + lc;
        *(bf16x8*)dst       = *(const bf16x8*)&lo[e][lc];
        *(bf16x8*)(dst + 8) = *(const bf16x8*)&lo[e][lc + 8];
    } else {
        const int row0 = blockIdx.x * 64 + wave * 16;

        const float* xr = x + (size_t)(row0 + m) * 64;
        float4 f0 = *(const float4*)(xr + q4 * 8);
        float4 f1 = *(const float4*)(xr + q4 * 8 + 4);
        float4 f2 = *(const float4*)(xr + 32 + q4 * 8);
        float4 f3 = *(const float4*)(xr + 32 + q4 * 8 + 4);
        bf16x8 a0 = cvt8(f0, f1);
        bf16x8 a1 = cvt8(f2, f3);

        floatx4 acc[4];
        #pragma unroll
        for (int sub = 0; sub < 4; ++sub) {
            bf16x8 b0 = load8bf(&wl[sub * 16 + m][q4 * 8]);
            bf16x8 b1 = load8bf(&wl[sub * 16 + m][32 + q4 * 8]);
            floatx4 z = {0.f, 0.f, 0.f, 0.f};
            z = __builtin_amdgcn_mfma_f32_16x16x32_bf16(a0, b0, z, 0, 0, 0);
            z = __builtin_amdgcn_mfma_f32_16x16x32_bf16(a1, b1, z, 0, 0, 0);
            acc[sub] = z;
        }

        // stage tile in natural [g_local][e] layout (scalar ds writes, 2-way max)
        #pragma unroll
        for (int sub = 0; sub < 4; ++sub) {
            #pragma unroll
            for (int r = 0; r < 4; ++r) {
                lo[wave * 16 + q4 * 4 + r][sub * 16 + m] = (bf16_t)acc[sub][r];
            }
        }
        __syncthreads();

        // coalesced vector store: thread t -> local row t>>2, 16-e chunk (t&3)*16
        const int gl = threadIdx.x >> 2;
        const int ec = (threadIdx.x & 3) * 16;
        const int g  = blockIdx.x * 64 + gl;
        const int n  = g >> 14;
        const int l  = (g >> 4) & 1023;
        const int h  = g & 15;
        const int nh = n * 16 + h;
        bf16_t* dst = ((op == 0) ? qp : kp) + ((size_t)nh * 1024 + l) * 64 + ec;
        *(bf16x8*)dst       = *(const bf16x8*)&lo[gl][ec];
        *(bf16x8*)(dst + 8) = *(const bf16x8*)&lo[gl][ec + 8];
    }
}

// ---------------------------------------------------------------------------
// Kernel 2: flash attention — BYTE-IDENTICAL to the round-5 passing version
// (128us, VGPR 64, validated).
// ---------------------------------------------------------------------------
__global__ __launch_bounds__(256) void attn_kernel(
    bf16_t* __restrict__ qp, const bf16_t* __restrict__ kp,
    const bf16_t* __restrict__ vt)
{
    __shared__ __align__(16) bf16_t kl[2][64][64];
    __shared__ __align__(16) bf16_t vl[2][64][64];

    const int lane = threadIdx.x & 63;
    const int wave = threadIdx.x >> 6;
    const int m  = lane & 15;
    const int q4 = lane >> 4;

    const int nh   = blockIdx.x & 127;   // same-nh blocks -> same XCD
    const int qblk = blockIdx.x >> 7;    // 0..15

    bf16_t* Q = qp + (size_t)nh * 65536;
    const bf16_t* K = kp + (size_t)nh * 65536;
    const bf16_t* V = vt + (size_t)nh * 65536;   // [D][L]

    const int qb = qblk * 64 + wave * 16;        // this wave's 16 queries

    const int srow  = lane >> 3;         // 0..7
    const int sslot = lane & 7;          // 0..7
    const int ch    = sslot ^ srow;      // pre-swizzled global chunk

    auto stage = [&](int b, int kb) {
        #pragma unroll
        for (int i = 0; i < 2; ++i) {
            const int rbase = wave * 16 + i * 8;
            const int row   = rbase + srow;
            __builtin_amdgcn_global_load_lds(
                (const __attribute__((address_space(1))) unsigned int*)(K + (size_t)(kb + row) * 64 + ch * 8),
                (__attribute__((address_space(3))) unsigned int*)(&kl[b][rbase][0]),
                16, 0, 0);
            __builtin_amdgcn_global_load_lds(
                (const __attribute__((address_space(1))) unsigned int*)(V + (size_t)row * 1024 + kb + ch * 8),
                (__attribute__((address_space(3))) unsigned int*)(&vl[b][rbase][0]),
                16, 0, 0);
        }
    };

    stage(0, 0);   // prologue: tile 0 in flight

    bf16x8 bqa = load8bf(Q + (qb + m) * 64 + q4 * 8);
    bf16x8 bqb = load8bf(Q + (qb + m) * 64 + 32 + q4 * 8);

    floatx4 o[4];
    #pragma unroll
    for (int i = 0; i < 4; ++i) o[i] = (floatx4){0.f, 0.f, 0.f, 0.f};
    float lsum = 0.f;
    const float CE = 1.4426950408889634f * 0.03125f;   // log2(e)/sqrt(1024)

    const int c0 = (q4 ^ (m & 7)) * 8;
    const int c1 = ((q4 + 4) ^ (m & 7)) * 8;
    const int hsel = q4 >> 1;

    int cur = 0;
    __syncthreads();   // drains prologue stage + barrier

    for (int kt = 0; kt < 16; ++kt) {
        if (kt < 15) stage(cur ^ 1, (kt + 1) * 64);   // next tile under compute

        floatx4 s[4];
        __builtin_amdgcn_s_setprio(1);
        #pragma unroll
        for (int sk = 0; sk < 4; ++sk) {
            bf16x8 ka0 = load8bf(&kl[cur][sk * 16 + m][c0]);
            bf16x8 ka1 = load8bf(&kl[cur][sk * 16 + m][c1]);
            floatx4 z = {0.f, 0.f, 0.f, 0.f};
            z = __builtin_amdgcn_mfma_f32_16x16x32_bf16(ka0, bqa, z, 0, 0, 0);
            z = __builtin_amdgcn_mfma_f32_16x16x32_bf16(ka1, bqb, z, 0, 0, 0);
            s[sk] = z;
        }
        __builtin_amdgcn_s_setprio(0);

        unsigned pk[2][4];
        #pragma unroll
        for (int c = 0; c < 2; ++c) {
            #pragma unroll
            for (int r = 0; r < 4; ++r) {
                float a0 = exp2f(s[2 * c][r] * CE);
                float a1 = exp2f(s[2 * c + 1][r] * CE);
                lsum += a0 + a1;
                PkU u; u.h[0] = (bf16_t)a0; u.h[1] = (bf16_t)a1;
                pk[c][r] = u.u;
            }
        }

        bf16x8 va[8];
        #pragma unroll
        for (int sd = 0; sd < 4; ++sd) {
            va[2 * sd]     = load8bf(&vl[cur][sd * 16 + m][c0]);
            va[2 * sd + 1] = load8bf(&vl[cur][sd * 16 + m][c1]);
        }

        bf16x8 bp[2];
        #pragma unroll
        for (int c = 0; c < 2; ++c) {
            #pragma unroll
            for (int j = 0; j < 8; ++j) {
                const int src = m + 16 * ((2 * q4 + (j >> 2)) & 3);
                PkU u; u.u = (unsigned)__shfl((int)pk[c][j & 3], src, 64);
                bp[c][j] = u.h[hsel];
            }
        }

        __builtin_amdgcn_s_setprio(1);
        #pragma unroll
        for (int sd = 0; sd < 4; ++sd) {
            o[sd] = __builtin_amdgcn_mfma_f32_16x16x32_bf16(va[2 * sd],     bp[0], o[sd], 0, 0, 0);
            o[sd] = __builtin_amdgcn_mfma_f32_16x16x32_bf16(va[2 * sd + 1], bp[1], o[sd], 0, 0, 0);
        }
        __builtin_amdgcn_s_setprio(0);

        __syncthreads();
        cur ^= 1;
    }

    lsum += __shfl_xor(lsum, 16, 64); lsum += __shfl_xor(lsum, 32, 64);
    const float inv = 1.0f / lsum;

    #pragma unroll
    for (int sd = 0; sd < 4; ++sd) {
        bf16x4 w;
        #pragma unroll
        for (int r = 0; r < 4; ++r) w[r] = (bf16_t)(o[sd][r] * inv);
        *(bf16x4*)(Q + (size_t)(qb + m) * 64 + sd * 16 + q4 * 4) = w;
    }
}

// ---------------------------------------------------------------------------
// Kernel 3a: one-shot Wo fp32 -> bf16 (into the dead vt region; r2-proven).
// ---------------------------------------------------------------------------
__global__ __launch_bounds__(256) void wocvt_kernel(
    const float* __restrict__ Wo, bf16_t* __restrict__ wo_bf)
{
    const int i = (blockIdx.x * 256 + threadIdx.x) * 8;
    float4 f0 = *(const float4*)(Wo + i);
    float4 f1 = *(const float4*)(Wo + i + 4);
    *(bf16x8*)(wo_bf + i) = cvt8(f0, f1);
}

// ---------------------------------------------------------------------------
// Kernel 3b: out(fp32) = AO @ Wo^T, 128x128 tiles, bf16 Wo staged in LDS.
// Grid 512 = (64 row-blocks) x (8 col-blocks); by = bid&7 puts each col-slice
// on one XCD -> its 256KB Wo slice is L2-resident (Wo traffic 512MB -> ~16MB).
// Fragment/store conventions identical to the validated 64x64 version.
// ---------------------------------------------------------------------------
__global__ __launch_bounds__(256) void outproj_kernel(
    const bf16_t* __restrict__ aoq, const bf16_t* __restrict__ wo_bf,
    float* __restrict__ out)
{
    __shared__ __align__(16) bf16_t wl[128][72];

    const int wave = threadIdx.x >> 6;
    const int lane = threadIdx.x & 63;
    const int m  = lane & 15;
    const int q4 = lane >> 4;

    const int bx = blockIdx.x >> 3;      // row-block 0..63
    const int by = blockIdx.x & 7;       // col-block 0..7 (XCD-resident slice)

    const int row0 = bx * 128 + wave * 32;   // this wave's 32 rows
    const int col0 = by * 128;

    const int ts_f = threadIdx.x >> 1;          // 0..127 (Wo col within tile)
    const int ts_k = (threadIdx.x & 1) * 32;    // k-half

    floatx4 acc[2][8];
    #pragma unroll
    for (int rs = 0; rs < 2; ++rs)
        #pragma unroll
        for (int cs = 0; cs < 8; ++cs) acc[rs][cs] = (floatx4){0.f, 0.f, 0.f, 0.f};

    for (int h = 0; h < 16; ++h) {
        const int kc = h * 64;
        __syncthreads();
        #pragma unroll
        for (int j = 0; j < 4; ++j) {
            *(bf16x8*)&wl[ts_f][ts_k + j * 8] =
                load8bf(wo_bf + (size_t)(col0 + ts_f) * 1024 + kc + ts_k + j * 8);
        }
        __syncthreads();

        // A fragments for this wave's 2 row-subtiles
        bf16x8 a[2][2];
        #pragma unroll
        for (int rs = 0; rs < 2; ++rs) {
            const int g = row0 + rs * 16 + m;
            const int n = g >> 10;
            const int q = g & 1023;
            const bf16_t* arow = aoq + ((size_t)(n * 16 + h) * 1024 + q) * 64;
            a[rs][0] = load8bf(arow + q4 * 8);
            a[rs][1] = load8bf(arow + 32 + q4 * 8);
        }

        #pragma unroll
        for (int cs = 0; cs < 8; ++cs) {
            bf16x8 b0 = load8bf(&wl[cs * 16 + m][q4 * 8]);
            bf16x8 b1 = load8bf(&wl[cs * 16 + m][32 + q4 * 8]);
            #pragma unroll
            for (int rs = 0; rs < 2; ++rs) {
                acc[rs][cs] = __builtin_amdgcn_mfma_f32_16x16x32_bf16(a[rs][0], b0, acc[rs][cs], 0, 0, 0);
                acc[rs][cs] = __builtin_amdgcn_mfma_f32_16x16x32_bf16(a[rs][1], b1, acc[rs][cs], 0, 0, 0);
            }
        }
    }

    #pragma unroll
    for (int rs = 0; rs < 2; ++rs) {
        #pragma unroll
        for (int r = 0; r < 4; ++r) {
            const int g = row0 + rs * 16 + q4 * 4 + r;
            #pragma unroll
            for (int cs = 0; cs < 8; ++cs)
                out[(size_t)g * 1024 + col0 + cs * 16 + m] = acc[rs][cs][r];
        }
    }
}

// ---------------------------------------------------------------------------
extern "C" void kernel_launch(void* const* d_in, const int* in_sizes, int n_in,
                              void* d_out, int out_size, void* d_ws, size_t ws_size,
                              hipStream_t stream) {
    const float* key   = (const float*)d_in[0];
    const float* query = (const float*)d_in[1];
    const float* value = (const float*)d_in[2];
    // d_in[3] = mask — faithfully ignored per the reference
    const float* Wq = (const float*)d_in[4];
    const float* Wk = (const float*)d_in[5];
    const float* Wv = (const float*)d_in[6];
    const float* Wo = (const float*)d_in[7];

    const size_t TENS = (size_t)NB * SEQ * EMB;   // 8388608
    bf16_t* qp = (bf16_t*)d_ws;                   // [N*H][L][D]; becomes AO in-place
    bf16_t* vt = qp + TENS;                       // [N*H][D][L]; reused for wo_bf after attn
    bf16_t* kp = (bf16_t*)d_out;                  // staged in d_out, dead before outproj

    hipLaunchKernelGGL(proj_kernel, dim3(2048, 3), dim3(256), 0, stream,
                       query, key, value, Wq, Wk, Wv, qp, kp, vt);
    hipLaunchKernelGGL(attn_kernel, dim3(2048), dim3(256), 0, stream, qp, kp, vt);
    hipLaunchKernelGGL(wocvt_kernel, dim3(512), dim3(256), 0, stream, Wo, vt);
    hipLaunchKernelGGL(outproj_kernel, dim3(512), dim3(256), 0, stream,
                       qp, vt, (float*)d_out);
}

// Round 7
// 264.824 us; speedup vs baseline: 1.7414x; 1.1365x over previous
//
#include <hip/hip_runtime.h>
#include <hip/hip_bf16.h>

#define HEADS 16
#define HDIM  64
#define EMB   1024
#define NB    8
#define SEQ   1024

typedef __bf16 bf16_t;
typedef __bf16 bf16x8 __attribute__((ext_vector_type(8)));
typedef __bf16 bf16x4 __attribute__((ext_vector_type(4)));
typedef float  floatx4 __attribute__((ext_vector_type(4)));
typedef float  f32x16  __attribute__((ext_vector_type(16)));

union PkU { unsigned u; __bf16 h[2]; };
union W4U { unsigned u[4]; bf16x8 v; };

__device__ __forceinline__ bf16x8 load8bf(const bf16_t* p) { return *(const bf16x8*)p; }
__device__ __forceinline__ bf16x4 cvt4(float4 a) {
    bf16x4 r; r[0]=(bf16_t)a.x; r[1]=(bf16_t)a.y; r[2]=(bf16_t)a.z; r[3]=(bf16_t)a.w;
    return r;
}
__device__ __forceinline__ bf16x8 cvt8(float4 a, float4 b) {
    bf16x8 r;
    r[0]=(bf16_t)a.x; r[1]=(bf16_t)a.y; r[2]=(bf16_t)a.z; r[3]=(bf16_t)a.w;
    r[4]=(bf16_t)b.x; r[5]=(bf16_t)b.y; r[6]=(bf16_t)b.z; r[7]=(bf16_t)b.w;
    return r;
}

// ---------------------------------------------------------------------------
// Kernel 1: per-head projections (byte-identical to round-6 passing version).
// ---------------------------------------------------------------------------
__global__ __launch_bounds__(256) void proj_kernel(
    const float* __restrict__ q_in, const float* __restrict__ k_in,
    const float* __restrict__ v_in,
    const float* __restrict__ Wq, const float* __restrict__ Wk,
    const float* __restrict__ Wv,
    bf16_t* __restrict__ qp, bf16_t* __restrict__ kp, bf16_t* __restrict__ vt)
{
    __shared__ __align__(16) bf16_t wl[64][72];
    __shared__ __align__(16) bf16_t lo[64][72];   // output staging

    const int wave = threadIdx.x >> 6;
    const int lane = threadIdx.x & 63;
    const int m  = lane & 15;
    const int q4 = lane >> 4;
    const int op = blockIdx.y;

    const float* x = (op == 0) ? q_in : (op == 1) ? k_in : v_in;
    const float* W = (op == 0) ? Wq   : (op == 1) ? Wk   : Wv;

    {
        const int t  = threadIdx.x;
        const int f  = t >> 2;
        const int kg = (t & 3) * 16;
        #pragma unroll
        for (int j = 0; j < 4; ++j) {
            float4 v = *(const float4*)(W + f * 64 + kg + j * 4);
            *(bf16x4*)&wl[f][kg + j * 4] = cvt4(v);
        }
    }
    __syncthreads();

    if (op == 2) {
        const int nh = blockIdx.x >> 4;          // 0..127
        const int l0 = (blockIdx.x & 15) * 64;
        const int n  = nh >> 4;
        const int h  = nh & 15;

        const int la = l0 + wave * 16 + m;
        const float* xr = x + (size_t)(n * 16384 + la * 16 + h) * 64;
        float4 f0 = *(const float4*)(xr + q4 * 8);
        float4 f1 = *(const float4*)(xr + q4 * 8 + 4);
        float4 f2 = *(const float4*)(xr + 32 + q4 * 8);
        float4 f3 = *(const float4*)(xr + 32 + q4 * 8 + 4);
        bf16x8 a0 = cvt8(f0, f1);
        bf16x8 a1 = cvt8(f2, f3);

        floatx4 acc[4];
        #pragma unroll
        for (int sub = 0; sub < 4; ++sub) {
            bf16x8 b0 = load8bf(&wl[sub * 16 + m][q4 * 8]);
            bf16x8 b1 = load8bf(&wl[sub * 16 + m][32 + q4 * 8]);
            floatx4 z = {0.f, 0.f, 0.f, 0.f};
            z = __builtin_amdgcn_mfma_f32_16x16x32_bf16(a0, b0, z, 0, 0, 0);
            z = __builtin_amdgcn_mfma_f32_16x16x32_bf16(a1, b1, z, 0, 0, 0);
            acc[sub] = z;
        }

        #pragma unroll
        for (int sub = 0; sub < 4; ++sub) {
            #pragma unroll
            for (int r = 0; r < 4; r += 2) {
                PkU u; u.h[0] = (bf16_t)acc[sub][r]; u.h[1] = (bf16_t)acc[sub][r + 1];
                *(unsigned*)&lo[sub * 16 + m][wave * 16 + q4 * 4 + r] = u.u;
            }
        }
        __syncthreads();

        const int e  = threadIdx.x >> 2;
        const int lc = (threadIdx.x & 3) * 16;
        bf16_t* dst = vt + ((size_t)nh * 64 + e) * 1024 + l0 + lc;
        *(bf16x8*)dst       = *(const bf16x8*)&lo[e][lc];
        *(bf16x8*)(dst + 8) = *(const bf16x8*)&lo[e][lc + 8];
    } else {
        const int row0 = blockIdx.x * 64 + wave * 16;

        const float* xr = x + (size_t)(row0 + m) * 64;
        float4 f0 = *(const float4*)(xr + q4 * 8);
        float4 f1 = *(const float4*)(xr + q4 * 8 + 4);
        float4 f2 = *(const float4*)(xr + 32 + q4 * 8);
        float4 f3 = *(const float4*)(xr + 32 + q4 * 8 + 4);
        bf16x8 a0 = cvt8(f0, f1);
        bf16x8 a1 = cvt8(f2, f3);

        floatx4 acc[4];
        #pragma unroll
        for (int sub = 0; sub < 4; ++sub) {
            bf16x8 b0 = load8bf(&wl[sub * 16 + m][q4 * 8]);
            bf16x8 b1 = load8bf(&wl[sub * 16 + m][32 + q4 * 8]);
            floatx4 z = {0.f, 0.f, 0.f, 0.f};
            z = __builtin_amdgcn_mfma_f32_16x16x32_bf16(a0, b0, z, 0, 0, 0);
            z = __builtin_amdgcn_mfma_f32_16x16x32_bf16(a1, b1, z, 0, 0, 0);
            acc[sub] = z;
        }

        // stage tile in natural [g_local][e] layout
        #pragma unroll
        for (int sub = 0; sub < 4; ++sub) {
            #pragma unroll
            for (int r = 0; r < 4; ++r) {
                lo[wave * 16 + q4 * 4 + r][sub * 16 + m] = (bf16_t)acc[sub][r];
            }
        }
        __syncthreads();

        const int gl = threadIdx.x >> 2;
        const int ec = (threadIdx.x & 3) * 16;
        const int g  = blockIdx.x * 64 + gl;
        const int n  = g >> 14;
        const int l  = (g >> 4) & 1023;
        const int h  = g & 15;
        const int nh = n * 16 + h;
        bf16_t* dst = ((op == 0) ? qp : kp) + ((size_t)nh * 1024 + l) * 64 + ec;
        *(bf16x8*)dst       = *(const bf16x8*)&lo[gl][ec];
        *(bf16x8*)(dst + 8) = *(const bf16x8*)&lo[gl][ec + 8];
    }
}

// ---------------------------------------------------------------------------
// Kernel 2: flash attention, 32x32 swapped-QK structure.
//  - each wave owns 32 queries; block = 4 waves = 128 q; grid 1024
//  - S^T = mfma_32x32x16(K-frag, Q-frag): lane holds P[32 keys] for ONE query
//    (col = lane&31); keys split lane vs lane+32
//  - P->B redistribution = 4 shfl_xor(.,32) per 32-key block (was 16 generic
//    bpermutes per 16q) -> 4x fewer shuffles per unit work
//  - K/V LDS staging, swizzle, double-buffer identical to r5/r6 (validated)
// C/D layout (guide, m74/m101): col=lane&31, row=(reg&3)+8*(reg>>2)+4*hi.
// A/B frag: row/col=lane&31, k=(lane>>5)*8+j.
// ---------------------------------------------------------------------------
__global__ __launch_bounds__(256) void attn_kernel(
    bf16_t* __restrict__ qp, const bf16_t* __restrict__ kp,
    const bf16_t* __restrict__ vt)
{
    __shared__ __align__(16) bf16_t kl[2][64][64];
    __shared__ __align__(16) bf16_t vl[2][64][64];

    const int lane = threadIdx.x & 63;
    const int wave = threadIdx.x >> 6;
    const int q32  = lane & 31;          // this lane's query column
    const int hi   = lane >> 5;          // half-wave id

    const int nh   = blockIdx.x & 127;   // same-nh blocks -> same XCD
    const int qblk = blockIdx.x >> 7;    // 0..7

    bf16_t* Q = qp + (size_t)nh * 65536;
    const bf16_t* K = kp + (size_t)nh * 65536;
    const bf16_t* V = vt + (size_t)nh * 65536;   // [D][L]

    const int qb = qblk * 128 + wave * 32;       // this wave's 32 queries

    // staging lane decomposition (unchanged from r5/r6)
    const int srow  = lane >> 3;
    const int sslot = lane & 7;
    const int ch    = sslot ^ srow;

    auto stage = [&](int b, int kb) {
        #pragma unroll
        for (int i = 0; i < 2; ++i) {
            const int rbase = wave * 16 + i * 8;
            const int row   = rbase + srow;
            __builtin_amdgcn_global_load_lds(
                (const __attribute__((address_space(1))) unsigned int*)(K + (size_t)(kb + row) * 64 + ch * 8),
                (__attribute__((address_space(3))) unsigned int*)(&kl[b][rbase][0]),
                16, 0, 0);
            __builtin_amdgcn_global_load_lds(
                (const __attribute__((address_space(1))) unsigned int*)(V + (size_t)row * 1024 + kb + ch * 8),
                (__attribute__((address_space(3))) unsigned int*)(&vl[b][rbase][0]),
                16, 0, 0);
        }
    };

    stage(0, 0);   // prologue: tile 0 in flight

    // Q B-fragments: col q = q32, k(d) = slice*16 + hi*8 + j
    bf16x8 bq[4];
    #pragma unroll
    for (int sl = 0; sl < 4; ++sl)
        bq[sl] = load8bf(Q + (size_t)(qb + q32) * 64 + sl * 16 + hi * 8);

    f32x16 o0 = {0.f,0.f,0.f,0.f,0.f,0.f,0.f,0.f,0.f,0.f,0.f,0.f,0.f,0.f,0.f,0.f};
    f32x16 o1 = o0;
    float lsum = 0.f;
    const float CE = 1.4426950408889634f * 0.03125f;   // log2(e)/sqrt(1024)

    int cur = 0;
    __syncthreads();   // drains prologue stage + barrier

    for (int kt = 0; kt < 16; ++kt) {
        if (kt < 15) stage(cur ^ 1, (kt + 1) * 64);   // next tile under compute

        #pragma unroll
        for (int kb32 = 0; kb32 < 2; ++kb32) {
            // ---- S^T[32k x 32q] over d=64 (4 slices) ----
            const int krow = kb32 * 32 + q32;
            f32x16 s = {0.f,0.f,0.f,0.f,0.f,0.f,0.f,0.f,0.f,0.f,0.f,0.f,0.f,0.f,0.f,0.f};
            __builtin_amdgcn_s_setprio(1);
            #pragma unroll
            for (int sl = 0; sl < 4; ++sl) {
                const int ck = ((sl * 2 + hi) ^ (krow & 7)) * 8;
                bf16x8 ka = load8bf(&kl[cur][krow][ck]);
                s = __builtin_amdgcn_mfma_f32_32x32x16_bf16(ka, bq[sl], s, 0, 0, 0);
            }
            __builtin_amdgcn_s_setprio(0);

            // ---- p = exp2(s*CE), pack pairs: w[t] rows (per C/D layout) ----
            unsigned w[8];
            #pragma unroll
            for (int t = 0; t < 8; ++t) {
                float p0 = exp2f(s[2 * t]     * CE);
                float p1 = exp2f(s[2 * t + 1] * CE);
                lsum += p0 + p1;
                PkU u; u.h[0] = (bf16_t)p0; u.h[1] = (bf16_t)p1;
                w[t] = u.u;
            }

            // ---- V fragments issued early (hide ds latency under shuffles) ----
            // A[row=d][k]: d = db*32+q32, k-chunk = kb32*4 + c*2 + hi
            bf16x8 va[4];
            #pragma unroll
            for (int db = 0; db < 2; ++db) {
                const int d = db * 32 + q32;
                #pragma unroll
                for (int c = 0; c < 2; ++c) {
                    const int cv = ((kb32 * 4 + c * 2 + hi) ^ (d & 7)) * 8;
                    va[db * 2 + c] = load8bf(&vl[cur][d][cv]);
                }
            }

            // ---- half-wave exchange: 4 shfl_xor(.,32) fills both sides ----
            const unsigned e0 = (unsigned)__shfl_xor((int)(hi ? w[0] : w[2]), 32, 64);
            const unsigned e1 = (unsigned)__shfl_xor((int)(hi ? w[1] : w[3]), 32, 64);
            const unsigned e2 = (unsigned)__shfl_xor((int)(hi ? w[4] : w[6]), 32, 64);
            const unsigned e3 = (unsigned)__shfl_xor((int)(hi ? w[5] : w[7]), 32, 64);

            // ---- B fragments: B[k][q], k = c*16 + hi*8 + j ----
            W4U b0v, b1v;
            b0v.u[0] = hi ? e0 : w[0];
            b0v.u[1] = hi ? e1 : w[1];
            b0v.u[2] = hi ? w[2] : e0;
            b0v.u[3] = hi ? w[3] : e1;
            b1v.u[0] = hi ? e2 : w[4];
            b1v.u[1] = hi ? e3 : w[5];
            b1v.u[2] = hi ? w[6] : e2;
            b1v.u[3] = hi ? w[7] : e3;

            // ---- O^T[d][q] += V^T-frag x P-frag ----
            __builtin_amdgcn_s_setprio(1);
            o0 = __builtin_amdgcn_mfma_f32_32x32x16_bf16(va[0], b0v.v, o0, 0, 0, 0);
            o0 = __builtin_amdgcn_mfma_f32_32x32x16_bf16(va[1], b1v.v, o0, 0, 0, 0);
            o1 = __builtin_amdgcn_mfma_f32_32x32x16_bf16(va[2], b0v.v, o1, 0, 0, 0);
            o1 = __builtin_amdgcn_mfma_f32_32x32x16_bf16(va[3], b1v.v, o1, 0, 0, 0);
            __builtin_amdgcn_s_setprio(0);
        }

        __syncthreads();   // stage(cur^1) complete + all reads of cur done
        cur ^= 1;
    }

    // final l reduction: keys split across lane/lane+32 only
    lsum += __shfl_xor(lsum, 32, 64);
    const float inv = 1.0f / lsum;

    // store O^T: reg r=4g+j -> d = db*32 + 8g + 4hi + j, col q = q32
    #pragma unroll
    for (int g = 0; g < 4; ++g) {
        bf16x4 w0v, w1v;
        #pragma unroll
        for (int r = 0; r < 4; ++r) {
            w0v[r] = (bf16_t)(o0[g * 4 + r] * inv);
            w1v[r] = (bf16_t)(o1[g * 4 + r] * inv);
        }
        *(bf16x4*)(Q + (size_t)(qb + q32) * 64 +      g * 8 + hi * 4) = w0v;
        *(bf16x4*)(Q + (size_t)(qb + q32) * 64 + 32 + g * 8 + hi * 4) = w1v;
    }
}

// ---------------------------------------------------------------------------
// Kernel 3a: one-shot Wo fp32 -> bf16 (into the dead vt region).
// ---------------------------------------------------------------------------
__global__ __launch_bounds__(256) void wocvt_kernel(
    const float* __restrict__ Wo, bf16_t* __restrict__ wo_bf)
{
    const int i = (blockIdx.x * 256 + threadIdx.x) * 8;
    float4 f0 = *(const float4*)(Wo + i);
    float4 f1 = *(const float4*)(Wo + i + 4);
    *(bf16x8*)(wo_bf + i) = cvt8(f0, f1);
}

// ---------------------------------------------------------------------------
// Kernel 3b: out(fp32) = AO @ Wo^T (byte-identical to round-6 passing version).
// ---------------------------------------------------------------------------
__global__ __launch_bounds__(256) void outproj_kernel(
    const bf16_t* __restrict__ aoq, const bf16_t* __restrict__ wo_bf,
    float* __restrict__ out)
{
    __shared__ __align__(16) bf16_t wl[128][72];

    const int wave = threadIdx.x >> 6;
    const int lane = threadIdx.x & 63;
    const int m  = lane & 15;
    const int q4 = lane >> 4;

    const int bx = blockIdx.x >> 3;      // row-block 0..63
    const int by = blockIdx.x & 7;       // col-block 0..7 (XCD-resident slice)

    const int row0 = bx * 128 + wave * 32;
    const int col0 = by * 128;

    const int ts_f = threadIdx.x >> 1;
    const int ts_k = (threadIdx.x & 1) * 32;

    floatx4 acc[2][8];
    #pragma unroll
    for (int rs = 0; rs < 2; ++rs)
        #pragma unroll
        for (int cs = 0; cs < 8; ++cs) acc[rs][cs] = (floatx4){0.f, 0.f, 0.f, 0.f};

    for (int h = 0; h < 16; ++h) {
        const int kc = h * 64;
        __syncthreads();
        #pragma unroll
        for (int j = 0; j < 4; ++j) {
            *(bf16x8*)&wl[ts_f][ts_k + j * 8] =
                load8bf(wo_bf + (size_t)(col0 + ts_f) * 1024 + kc + ts_k + j * 8);
        }
        __syncthreads();

        bf16x8 a[2][2];
        #pragma unroll
        for (int rs = 0; rs < 2; ++rs) {
            const int g = row0 + rs * 16 + m;
            const int n = g >> 10;
            const int q = g & 1023;
            const bf16_t* arow = aoq + ((size_t)(n * 16 + h) * 1024 + q) * 64;
            a[rs][0] = load8bf(arow + q4 * 8);
            a[rs][1] = load8bf(arow + 32 + q4 * 8);
        }

        #pragma unroll
        for (int cs = 0; cs < 8; ++cs) {
            bf16x8 b0 = load8bf(&wl[cs * 16 + m][q4 * 8]);
            bf16x8 b1 = load8bf(&wl[cs * 16 + m][32 + q4 * 8]);
            #pragma unroll
            for (int rs = 0; rs < 2; ++rs) {
                acc[rs][cs] = __builtin_amdgcn_mfma_f32_16x16x32_bf16(a[rs][0], b0, acc[rs][cs], 0, 0, 0);
                acc[rs][cs] = __builtin_amdgcn_mfma_f32_16x16x32_bf16(a[rs][1], b1, acc[rs][cs], 0, 0, 0);
            }
        }
    }

    #pragma unroll
    for (int rs = 0; rs < 2; ++rs) {
        #pragma unroll
        for (int r = 0; r < 4; ++r) {
            const int g = row0 + rs * 16 + q4 * 4 + r;
            #pragma unroll
            for (int cs = 0; cs < 8; ++cs)
                out[(size_t)g * 1024 + col0 + cs * 16 + m] = acc[rs][cs][r];
        }
    }
}

// ---------------------------------------------------------------------------
extern "C" void kernel_launch(void* const* d_in, const int* in_sizes, int n_in,
                              void* d_out, int out_size, void* d_ws, size_t ws_size,
                              hipStream_t stream) {
    const float* key   = (const float*)d_in[0];
    const float* query = (const float*)d_in[1];
    const float* value = (const float*)d_in[2];
    // d_in[3] = mask — faithfully ignored per the reference
    const float* Wq = (const float*)d_in[4];
    const float* Wk = (const float*)d_in[5];
    const float* Wv = (const float*)d_in[6];
    const float* Wo = (const float*)d_in[7];

    const size_t TENS = (size_t)NB * SEQ * EMB;   // 8388608
    bf16_t* qp = (bf16_t*)d_ws;                   // [N*H][L][D]; becomes AO in-place
    bf16_t* vt = qp + TENS;                       // [N*H][D][L]; reused for wo_bf after attn
    bf16_t* kp = (bf16_t*)d_out;                  // staged in d_out, dead before outproj

    hipLaunchKernelGGL(proj_kernel, dim3(2048, 3), dim3(256), 0, stream,
                       query, key, value, Wq, Wk, Wv, qp, kp, vt);
    hipLaunchKernelGGL(attn_kernel, dim3(1024), dim3(256), 0, stream, qp, kp, vt);
    hipLaunchKernelGGL(wocvt_kernel, dim3(512), dim3(256), 0, stream, Wo, vt);
    hipLaunchKernelGGL(outproj_kernel, dim3(512), dim3(256), 0, stream,
                       qp, vt, (float*)d_out);
}